// Round 14
// baseline (232.577 us; speedup 1.0000x reference)
//
#include <hip/hip_runtime.h>
#include <cmath>

typedef unsigned short u16;
typedef short v8s __attribute__((ext_vector_type(8)));
typedef float v4f __attribute__((ext_vector_type(4)));
typedef unsigned short v4u __attribute__((ext_vector_type(4)));
typedef unsigned int v2u __attribute__((ext_vector_type(2)));

__device__ __forceinline__ u16 f2bf(float f) {
  unsigned u = __builtin_bit_cast(unsigned, f);
  u += 0x7fffu + ((u >> 16) & 1u);
  return (u16)(u >> 16);
}
__device__ __forceinline__ float bf2f(u16 h) {
  unsigned u = ((unsigned)h) << 16;
  return __builtin_bit_cast(float, u);
}
// T12: hardware packed f32->bf16x2
__device__ __forceinline__ unsigned pk2(float a, float b) {
  unsigned r;
  asm("v_cvt_pk_bf16_f32 %0, %1, %2" : "=v"(r) : "v"(a), "v"(b));
  return r;
}

// ---------------- cast fp32 -> bf16 (vectorized, G13) ----------------
__global__ void k_cast_bf16(const float* __restrict__ in, u16* __restrict__ out, int n4) {
  int i = blockIdx.x * blockDim.x + threadIdx.x;
  if (i >= n4) return;
  v4f v = ((const v4f*)in)[i];
  v4u o;
  o[0] = f2bf(v[0]); o[1] = f2bf(v[1]); o[2] = f2bf(v[2]); o[3] = f2bf(v[3]);
  ((v4u*)out)[i] = o;
}

// ---------------- fused cast of the 4 weight tensors ----------------
__global__ void k_cast_w(const float* __restrict__ a, const float* __restrict__ b,
                         const float* __restrict__ c, const float* __restrict__ d,
                         u16* __restrict__ oa, u16* __restrict__ ob, u16* __restrict__ oc,
                         u16* __restrict__ od, int na4, int nb4, int nc4, int nd4) {
  int j = blockIdx.x * blockDim.x + threadIdx.x;
  const float* src;
  u16* dst;
  if (j < na4) { src = a; dst = oa; }
  else {
    j -= na4;
    if (j < nb4) { src = b; dst = ob; }
    else {
      j -= nb4;
      if (j < nc4) { src = c; dst = oc; }
      else {
        j -= nc4;
        if (j >= nd4) return;
        src = d; dst = od;
      }
    }
  }
  v4f v = ((const v4f*)src)[j];
  v4u o;
  o[0] = f2bf(v[0]); o[1] = f2bf(v[1]); o[2] = f2bf(v[2]); o[3] = f2bf(v[3]);
  ((v4u*)dst)[j] = o;
}

// ---------------- RoPE cos/sin table [S][64] f32 ----------------
__global__ void k_rope_tab(float* __restrict__ cosT, float* __restrict__ sinT, float log2_base) {
  int idx = blockIdx.x * blockDim.x + threadIdx.x;
  int t = idx >> 6, i = idx & 63;
  float inv = exp2f(-(float)i * (1.0f / 64.0f) * log2_base);
  float fr = (float)t * inv;
  cosT[idx] = cosf(fr);
  sinT[idx] = sinf(fr);
}

// ------ per-head RMSNorm + RoPE + gain + output scale (in-place, bf16) -------
__global__ void k_rmsnorm_rope(u16* __restrict__ qk, const float* __restrict__ cosT,
                               const float* __restrict__ sinT, const float* __restrict__ gain,
                               int H, int S, float oscale) {
  int row = blockIdx.x * 4 + (threadIdx.x >> 6);
  int l = threadIdx.x & 63;
  int h = row % H;
  int m = row / H;
  int s = m % S;
  u16* p = qk + (size_t)row * 128;
  float a = bf2f(p[l]), b = bf2f(p[64 + l]);
  float ss = a * a + b * b;
#pragma unroll
  for (int o = 32; o; o >>= 1) ss += __shfl_xor(ss, o, 64);
  float r = rsqrtf(ss * (1.0f / 128.0f) + 1.1920929e-7f);
  a *= r; b *= r;
  float c = cosT[s * 64 + l], sn = sinT[s * 64 + l];
  float o1 = a * c + b * sn;
  float o2 = b * c - a * sn;
  float g = oscale;
  if (gain != nullptr) g *= gain[h];
  p[l] = f2bf(o1 * g);
  p[64 + l] = f2bf(o2 * g);
}

// ======== 128x384 8-phase QKV GEMM (T1+T2+T3+T4+T5), BK=64, 512 thr =========
__device__ __forceinline__ void stage8(char* sL, const u16* __restrict__ Ag,
                                       const u16* __restrict__ Bg, int row0, int col0, int K,
                                       int n, int NT2, int tid) {
  int tile = n >> 2;
  if (tile >= NT2) return;
  int part = n & 3;  // 0:A-h0 1:B-h1 2:A-h1 3:B-h0
  int isB = part & 1;
  int half = (part == 1 || part == 2) ? 1 : 0;
  int k0 = tile * 64;
  if (!isB) {
    char* base = sL + (tile & 1) * 65536 + half * 8192;
    int o = tid * 16;
    int rowp = o >> 8;
    int un = (o & 255) ^ ((rowp & 15) << 4);
    int rsub = rowp + ((un >> 7) << 5);
    int k = (un & 127) >> 1;
    const u16* src = Ag + (size_t)(row0 + half * 64 + rsub) * K + (k0 + k);
    __builtin_amdgcn_global_load_lds((const __attribute__((address_space(1))) void*)src,
                                     (__attribute__((address_space(3))) void*)(base + o), 16, 0, 0);
  } else {
    char* base = sL + (tile & 1) * 65536 + 16384 + half * 24576;
#pragma unroll
    for (int j = 0; j < 3; ++j) {
      int o = (j * 512 + tid) * 16;
      int rowp = o >> 8;
      int un = (o & 255) ^ ((rowp & 15) << 4);
      int rsub = rowp + (un >> 7) * 96;
      int k = (un & 127) >> 1;
      const u16* src = Bg + (size_t)(col0 + half * 192 + rsub) * K + (k0 + k);
      __builtin_amdgcn_global_load_lds((const __attribute__((address_space(1))) void*)src,
                                       (__attribute__((address_space(3))) void*)(base + o), 16, 0,
                                       0);
    }
  }
}

#define PH(BUF, MH, NH, LA, LB, WAITC)                                                            \
  {                                                                                               \
    if (LA) {                                                                                     \
      _Pragma("unroll") for (int mi = 0; mi < 2; ++mi) {                                          \
        _Pragma("unroll") for (int c = 0; c < 2; ++c) {                                           \
          af[mi][c] = *(const v8s*)(sL + (BUF)*65536 + (MH)*8192 + (mi * 16 + lr) * 256 +         \
                                    ((wm * 128 + c * 64 + lh * 16) ^ (lr << 4)));                 \
        }                                                                                         \
      }                                                                                           \
    }                                                                                             \
    if (LB) {                                                                                     \
      _Pragma("unroll") for (int ni = 0; ni < 3; ++ni) {                                          \
        _Pragma("unroll") for (int c = 0; c < 2; ++c) {                                           \
          bf[ni][c] = *(const v8s*)(sL + (BUF)*65536 + 16384 + (NH)*24576 +                       \
                                    ((wn & 1) * 48 + ni * 16 + lr) * 256 +                        \
                                    (((wn >> 1) * 128 + c * 64 + lh * 16) ^ (lr << 4)));          \
        }                                                                                         \
      }                                                                                           \
    }                                                                                             \
    stage8(sL, Ag, Bg, row0, col0, K, n, NT2, tid);                                               \
    ++n;                                                                                          \
    if (WAITC) {                                                                                  \
      if (((n - 1) >> 2) < NT2) asm volatile("s_waitcnt vmcnt(4)" ::: "memory");                  \
      else asm volatile("s_waitcnt vmcnt(0)" ::: "memory");                                       \
    }                                                                                             \
    __builtin_amdgcn_sched_barrier(0);                                                            \
    __builtin_amdgcn_s_barrier();                                                                 \
    asm volatile("s_waitcnt lgkmcnt(0)" ::: "memory");                                            \
    __builtin_amdgcn_sched_barrier(0);                                                            \
    __builtin_amdgcn_s_setprio(1);                                                                \
    _Pragma("unroll") for (int mi = 0; mi < 2; ++mi) {                                            \
      _Pragma("unroll") for (int ni = 0; ni < 3; ++ni) {                                          \
        _Pragma("unroll") for (int c = 0; c < 2; ++c) {                                           \
          acc[(MH)*2 + mi][(NH)*3 + ni] = __builtin_amdgcn_mfma_f32_16x16x32_bf16(                \
              af[mi][c], bf[ni][c], acc[(MH)*2 + mi][(NH)*3 + ni], 0, 0, 0);                      \
        }                                                                                         \
      }                                                                                           \
    }                                                                                             \
    __builtin_amdgcn_s_setprio(0);                                                                \
    __builtin_amdgcn_sched_barrier(0);                                                            \
    __builtin_amdgcn_s_barrier();                                                                 \
  }

__global__ __launch_bounds__(512, 2) void k_gemm_qkv8(const u16* __restrict__ Ag,
                                                      const u16* __restrict__ Bg,
                                                      u16* __restrict__ q_o, u16* __restrict__ k_o,
                                                      u16* __restrict__ v_o, int M, int K) {
  __shared__ char sL[131072];
  const int tid = threadIdx.x;
  const int wid = tid >> 6, l = tid & 63;
  const int lr = l & 15, lh = l >> 4;
  const int wm = wid >> 2, wn = wid & 3;
  const int nwg = gridDim.x * gridDim.y;
  const int bid = blockIdx.y * gridDim.x + blockIdx.x;
  const int cpx = nwg >> 3;
  const int swz = (bid & 7) * cpx + (bid >> 3);
  const int row0 = (swz / gridDim.x) * 128, col0 = (swz % gridDim.x) * 384;
  const int NT2 = K >> 6;

  v4f zz = {0.f, 0.f, 0.f, 0.f};
  v4f acc[4][6];
#pragma unroll
  for (int i = 0; i < 4; ++i)
#pragma unroll
    for (int j = 0; j < 6; ++j) acc[i][j] = zz;
  v8s af[2][2], bf[3][2];

  for (int i = 0; i < 6; ++i) stage8(sL, Ag, Bg, row0, col0, K, i, NT2, tid);
  asm volatile("s_waitcnt vmcnt(4)" ::: "memory");
  __builtin_amdgcn_sched_barrier(0);
  __builtin_amdgcn_s_barrier();

  int n = 6;
  for (int it = 0; it < NT2 / 2; ++it) {
    PH(0, 0, 0, 1, 1, 0)
    PH(0, 0, 1, 0, 1, 0)
    PH(0, 1, 1, 1, 0, 0)
    PH(0, 1, 0, 0, 1, 1)
    PH(1, 0, 0, 1, 1, 0)
    PH(1, 0, 1, 0, 1, 0)
    PH(1, 1, 1, 1, 0, 0)
    PH(1, 1, 0, 0, 1, 1)
  }

#pragma unroll
  for (int MH = 0; MH < 2; ++MH) {
#pragma unroll
    for (int mi = 0; mi < 2; ++mi) {
#pragma unroll
      for (int NH = 0; NH < 2; ++NH) {
#pragma unroll
        for (int ni = 0; ni < 3; ++ni) {
          int row = row0 + MH * 64 + wm * 32 + mi * 16 + lh * 4;
          int col = col0 + NH * 192 + wn * 48 + ni * 16 + lr;
          v4f a_ = acc[MH * 2 + mi][NH * 3 + ni];
          if (col < 2048) {
#pragma unroll
            for (int r = 0; r < 4; ++r) q_o[(size_t)(row + r) * 2048 + col] = f2bf(a_[r]);
          } else if (col < 2560) {
#pragma unroll
            for (int r = 0; r < 4; ++r) k_o[(size_t)(row + r) * 512 + (col - 2048)] = f2bf(a_[r]);
          } else {
#pragma unroll
            for (int r = 0; r < 4; ++r) v_o[(size_t)(col - 2560) * M + row + r] = f2bf(a_[r]);
          }
        }
      }
    }
  }
}

// ======== 128x256 8-phase out-proj GEMM (f32 C), BK=64, 512 thr =========
__device__ __forceinline__ void stage8b(char* sL, const u16* __restrict__ Ag,
                                        const u16* __restrict__ Bg, int row0, int col0, int K,
                                        int n, int NT2, int tid) {
  int tile = n >> 2;
  if (tile >= NT2) return;
  int part = n & 3;
  int isB = part & 1;
  int half = (part == 1 || part == 2) ? 1 : 0;
  int k0 = tile * 64;
  if (!isB) {
    char* base = sL + (tile & 1) * 49152 + half * 8192;
    int o = tid * 16;
    int rowp = o >> 8;
    int un = (o & 255) ^ ((rowp & 15) << 4);
    int rsub = rowp + ((un >> 7) << 5);
    int k = (un & 127) >> 1;
    const u16* src = Ag + (size_t)(row0 + half * 64 + rsub) * K + (k0 + k);
    __builtin_amdgcn_global_load_lds((const __attribute__((address_space(1))) void*)src,
                                     (__attribute__((address_space(3))) void*)(base + o), 16, 0, 0);
  } else {
    char* base = sL + (tile & 1) * 49152 + 16384 + half * 16384;
#pragma unroll
    for (int j = 0; j < 2; ++j) {
      int o = (j * 512 + tid) * 16;
      int rowp = o >> 8;
      int un = (o & 255) ^ ((rowp & 15) << 4);
      int rsub = rowp + (un >> 7) * 64;
      int k = (un & 127) >> 1;
      const u16* src = Bg + (size_t)(col0 + half * 128 + rsub) * K + (k0 + k);
      __builtin_amdgcn_global_load_lds((const __attribute__((address_space(1))) void*)src,
                                       (__attribute__((address_space(3))) void*)(base + o), 16, 0,
                                       0);
    }
  }
}

#define PH2(BUF, MH, NH, LA, LB, WAITC)                                                           \
  {                                                                                               \
    if (LA) {                                                                                     \
      _Pragma("unroll") for (int mi = 0; mi < 2; ++mi) {                                          \
        _Pragma("unroll") for (int c = 0; c < 2; ++c) {                                           \
          af[mi][c] = *(const v8s*)(sL + (BUF)*49152 + (MH)*8192 + (mi * 16 + lr) * 256 +         \
                                    ((wm * 128 + c * 64 + lh * 16) ^ (lr << 4)));                 \
        }                                                                                         \
      }                                                                                           \
    }                                                                                             \
    if (LB) {                                                                                     \
      _Pragma("unroll") for (int ni = 0; ni < 2; ++ni) {                                          \
        _Pragma("unroll") for (int c = 0; c < 2; ++c) {                                           \
          bf[ni][c] = *(const v8s*)(sL + (BUF)*49152 + 16384 + (NH)*16384 +                       \
                                    ((wn & 1) * 32 + ni * 16 + lr) * 256 +                        \
                                    (((wn >> 1) * 128 + c * 64 + lh * 16) ^ (lr << 4)));          \
        }                                                                                         \
      }                                                                                           \
    }                                                                                             \
    stage8b(sL, Ag, Bg, row0, col0, K, n, NT2, tid);                                              \
    ++n;                                                                                          \
    if (WAITC) {                                                                                  \
      if (((n - 1) >> 2) < NT2) asm volatile("s_waitcnt vmcnt(3)" ::: "memory");                  \
      else asm volatile("s_waitcnt vmcnt(0)" ::: "memory");                                       \
    }                                                                                             \
    __builtin_amdgcn_sched_barrier(0);                                                            \
    __builtin_amdgcn_s_barrier();                                                                 \
    asm volatile("s_waitcnt lgkmcnt(0)" ::: "memory");                                            \
    __builtin_amdgcn_sched_barrier(0);                                                            \
    __builtin_amdgcn_s_setprio(1);                                                                \
    _Pragma("unroll") for (int mi = 0; mi < 2; ++mi) {                                            \
      _Pragma("unroll") for (int ni = 0; ni < 2; ++ni) {                                          \
        _Pragma("unroll") for (int c = 0; c < 2; ++c) {                                           \
          acc[(MH)*2 + mi][(NH)*2 + ni] = __builtin_amdgcn_mfma_f32_16x16x32_bf16(                \
              af[mi][c], bf[ni][c], acc[(MH)*2 + mi][(NH)*2 + ni], 0, 0, 0);                      \
        }                                                                                         \
      }                                                                                           \
    }                                                                                             \
    __builtin_amdgcn_s_setprio(0);                                                                \
    __builtin_amdgcn_sched_barrier(0);                                                            \
    __builtin_amdgcn_s_barrier();                                                                 \
  }

__global__ __launch_bounds__(512, 2) void k_gemm_bt8(const u16* __restrict__ Ag,
                                                     const u16* __restrict__ Bg,
                                                     float* __restrict__ C, int M, int N, int K) {
  __shared__ char sL[98304];
  const int tid = threadIdx.x;
  const int wid = tid >> 6, l = tid & 63;
  const int lr = l & 15, lh = l >> 4;
  const int wm = wid >> 2, wn = wid & 3;
  const int nwg = gridDim.x * gridDim.y;
  const int bid = blockIdx.y * gridDim.x + blockIdx.x;
  const int cpx = nwg >> 3;
  const int swz = (bid & 7) * cpx + (bid >> 3);
  const int row0 = (swz / gridDim.x) * 128, col0 = (swz % gridDim.x) * 256;
  const int NT2 = K >> 6;

  v4f zz = {0.f, 0.f, 0.f, 0.f};
  v4f acc[4][4];
#pragma unroll
  for (int i = 0; i < 4; ++i)
#pragma unroll
    for (int j = 0; j < 4; ++j) acc[i][j] = zz;
  v8s af[2][2], bf[2][2];

  for (int i = 0; i < 6; ++i) stage8b(sL, Ag, Bg, row0, col0, K, i, NT2, tid);
  asm volatile("s_waitcnt vmcnt(3)" ::: "memory");
  __builtin_amdgcn_sched_barrier(0);
  __builtin_amdgcn_s_barrier();

  int n = 6;
  for (int it = 0; it < NT2 / 2; ++it) {
    PH2(0, 0, 0, 1, 1, 0)
    PH2(0, 0, 1, 0, 1, 0)
    PH2(0, 1, 1, 1, 0, 0)
    PH2(0, 1, 0, 0, 1, 1)
    PH2(1, 0, 0, 1, 1, 0)
    PH2(1, 0, 1, 0, 1, 0)
    PH2(1, 1, 1, 1, 0, 0)
    PH2(1, 1, 0, 0, 1, 1)
  }

#pragma unroll
  for (int MH = 0; MH < 2; ++MH) {
#pragma unroll
    for (int mi = 0; mi < 2; ++mi) {
#pragma unroll
      for (int NH = 0; NH < 2; ++NH) {
#pragma unroll
        for (int ni = 0; ni < 2; ++ni) {
          int row = row0 + MH * 64 + wm * 32 + mi * 16 + lh * 4;
          int col = col0 + NH * 128 + (wn & 1) * 32 + (wn >> 1) * 64 + ni * 16 + lr;
          v4f a_ = acc[MH * 2 + mi][NH * 2 + ni];
#pragma unroll
          for (int r = 0; r < 4; ++r) C[(size_t)(row + r) * N + col] = a_[r];
        }
      }
    }
  }
}

// ------- causal GQA flash attention v12: KVBLK=32, 3-4 blocks/CU ------------
// LDS ~37KB (sK 2x8K [32kv x 256B], sV 2x8K [128d x 64B], P stride-20) ->
// 3-4 blocks/CU co-resident (was 2 at 72KB). Stage next tile at loop TOP so
// the end-of-tile vmcnt drain window is a full tile (> HBM latency).
__global__ __launch_bounds__(256) void k_flash_attn(const u16* __restrict__ Q,
                                                    const u16* __restrict__ Kb,
                                                    const u16* __restrict__ Vt,
                                                    u16* __restrict__ O, int S, int H, int KH,
                                                    int Mtot) {
  const int bh = blockIdx.x;
  const int h = bh % H, b = bh / H;
  const int kvh = h / (H / KH);
  const int w = threadIdx.x >> 6, l = threadIdx.x & 63;
  const int lr = l & 15, lh = l >> 4;

  __shared__ alignas(16) char sK[2][8192];            // 32 kv x 256B, XOR-swizzled
  __shared__ alignas(16) char sV[2][8192];            // 128 d x 64B, XOR-swizzled
  __shared__ alignas(16) unsigned P_lds[4][16 * 20];  // per-wave packed P, stride 20
  unsigned* prow = P_lds[w] + lr * 20;
  const int xr = (lr & 3) << 2;

  v4f zz = {0.f, 0.f, 0.f, 0.f};
  const int strideK = KH * 128;
  const int strideKB = strideK * 2;
  const char* KheadB = (const char*)Kb + 2 * ((size_t)b * S * strideK + (size_t)kvh * 128);
  const char* VheadB = (const char*)Vt + 2 * ((size_t)(kvh * 128) * Mtot + (size_t)b * S);
  const size_t MtotB = (size_t)Mtot * 2;

  // stage K tile (32 x 256B) + V tile (128 x 64B) for kv0 into buf (2 issues each)
  auto stage = [&](int kv0, int bufi) {
    const char* Kt = KheadB + (size_t)kv0 * strideKB;
#pragma unroll
    for (int j = 0; j < 2; ++j) {
      int jj = w * 2 + j;
      int ci = jj * 64 + l;
      int r = ci >> 4;
      int bc = (ci & 15) << 4;
      const char* src = Kt + (size_t)r * strideKB + (bc ^ ((r & 15) << 4));
      __builtin_amdgcn_global_load_lds((const __attribute__((address_space(1))) void*)src,
                                       (__attribute__((address_space(3))) void*)(sK[bufi] + jj * 1024),
                                       16, 0, 0);
    }
    const char* Vt0 = VheadB + (size_t)kv0 * 2;
#pragma unroll
    for (int j = 0; j < 2; ++j) {
      int jj = w * 2 + j;
      int ci = jj * 64 + l;
      int r = ci >> 2;
      int bc = (ci & 3) << 4;
      const char* src = Vt0 + (size_t)r * MtotB + (bc ^ ((r & 3) << 4));
      __builtin_amdgcn_global_load_lds((const __attribute__((address_space(1))) void*)src,
                                       (__attribute__((address_space(3))) void*)(sV[bufi] + jj * 1024),
                                       16, 0, 0);
    }
  };

  for (int pp = 0; pp < 2; ++pp) {
    const int qt = (pp == 0) ? (int)blockIdx.y : (S / 64 - 1 - (int)blockIdx.y);
    const int q0 = qt * 64;
    const int nt = 2 * qt + 2;  // 32-wide kv tiles
    const int qi = q0 + w * 16 + lr;

    v8s qf[4];
    const u16* qp = Q + (size_t)(b * S + q0 + w * 16 + lr) * (size_t)(H * 128) + h * 128 + lh * 8;
#pragma unroll
    for (int c = 0; c < 4; ++c) qf[c] = *(const v8s*)(qp + c * 32);

    v4f o_acc[8];
#pragma unroll
    for (int df = 0; df < 8; ++df) o_acc[df] = zz;
    float m_run = -1e30f, l_run = 0.f;

    stage(0, 0);
    __syncthreads();

    int buf = 0;
    for (int t = 0; t < nt; ++t) {
      const int kv0 = t * 32;
      const char* sKb = sK[buf];
      const char* sVb = sV[buf];

      // ---- stage next tile FIRST (full-tile latency window) ----
      if (t + 1 < nt) stage(kv0 + 32, buf ^ 1);

      // ---- QK^T swapped (C rows=kv, cols=q), K from LDS ----
      v4f sv[2];
      __builtin_amdgcn_s_setprio(1);
#pragma unroll
      for (int nf = 0; nf < 2; ++nf) {
        v4f a_ = zz;
        const int r = nf * 16 + lr;
#pragma unroll
        for (int c = 0; c < 4; ++c) {
          v8s kf = *(const v8s*)(sKb + r * 256 + ((lh * 16 + c * 64) ^ (lr << 4)));
          a_ = __builtin_amdgcn_mfma_f32_16x16x32_bf16(kf, qf[c], a_, 0, 0, 0);
        }
        sv[nf] = a_;
      }
      __builtin_amdgcn_s_setprio(0);

      // ---- in-lane online softmax ----
      if (kv0 + 31 > q0) {  // diagonal tiles only (block-uniform gate)
#pragma unroll
        for (int nf = 0; nf < 2; ++nf)
#pragma unroll
          for (int r = 0; r < 4; ++r)
            if (kv0 + nf * 16 + lh * 4 + r > qi) sv[nf][r] = -1e30f;
      }
      float pm0 = fmaxf(fmaxf(sv[0][0], sv[0][1]), fmaxf(sv[0][2], sv[0][3]));
      float pm1 = fmaxf(fmaxf(sv[1][0], sv[1][1]), fmaxf(sv[1][2], sv[1][3]));
      float pmax = fmaxf(pm0, pm1);
      pmax = fmaxf(pmax, __shfl_xor(pmax, 16, 64));
      pmax = fmaxf(pmax, __shfl_xor(pmax, 32, 64));
      if (!__all(pmax - m_run <= 8.0f)) {  // T13 defer-max
        float mnew = fmaxf(m_run, pmax);
        float corr = exp2f(m_run - mnew);
        l_run *= corr;
        m_run = mnew;
        float corrq[4];
#pragma unroll
        for (int r = 0; r < 4; ++r) corrq[r] = __shfl(corr, lh * 4 + r, 16);
#pragma unroll
        for (int df = 0; df < 8; ++df)
#pragma unroll
          for (int r = 0; r < 4; ++r) o_acc[df][r] *= corrq[r];
      }
      float rsum = 0.f;
#pragma unroll
      for (int nf = 0; nf < 2; ++nf)
#pragma unroll
        for (int r = 0; r < 4; ++r) {
          float pv = exp2f(sv[nf][r] - m_run);
          sv[nf][r] = pv;
          rsum += pv;
        }
      rsum += __shfl_xor(rsum, 16, 64);
      rsum += __shfl_xor(rsum, 32, 64);
      l_run += rsum;

      // ---- pack P (4 words) -> per-wave LDS, reload as single A-frag ----
#pragma unroll
      for (int nf = 0; nf < 2; ++nf) {
        v2u pw;
        pw[0] = pk2(sv[nf][0], sv[nf][1]);
        pw[1] = pk2(sv[nf][2], sv[nf][3]);
        *(v2u*)(prow + ((nf * 8 + lh * 2) ^ xr)) = pw;
      }
      asm volatile("s_waitcnt lgkmcnt(0)" ::: "memory");
      __builtin_amdgcn_sched_barrier(0);  // rule 18
      v8s ap = *(const v8s*)(prow + ((lh * 4) ^ xr));

      // ---- PV: V from LDS (swizzled ds_read_b128, one chunk: K=32) ----
      __builtin_amdgcn_s_setprio(1);
#pragma unroll
      for (int df = 0; df < 8; ++df) {
        const int r = df * 16 + lr;
        v8s vf = *(const v8s*)(sVb + r * 64 + ((lh * 16) ^ ((r & 3) << 4)));
        o_acc[df] = __builtin_amdgcn_mfma_f32_16x16x32_bf16(ap, vf, o_acc[df], 0, 0, 0);
      }
      __builtin_amdgcn_s_setprio(0);

      __syncthreads();  // drains own staging (window = full tile); buf swap safe
      buf ^= 1;
    }

    float rl = 1.0f / l_run;
    float invq[4];
#pragma unroll
    for (int r = 0; r < 4; ++r) invq[r] = __shfl(rl, lh * 4 + r, 16);
    u16* op = O + (size_t)(b * S + q0 + w * 16 + lh * 4) * (size_t)(H * 128) + h * 128;
#pragma unroll
    for (int r = 0; r < 4; ++r)
#pragma unroll
      for (int df = 0; df < 8; ++df)
        op[(size_t)r * (H * 128) + df * 16 + lr] = f2bf(o_acc[df][r] * invq[r]);
  }
}

extern "C" void kernel_launch(void* const* d_in, const int* in_sizes, int n_in, void* d_out,
                              int out_size, void* d_ws, size_t ws_size, hipStream_t stream) {
  const float* x = (const float*)d_in[0];
  const float* Wq = (const float*)d_in[1];
  const float* Wk = (const float*)d_in[2];
  const float* Wv = (const float*)d_in[3];
  const float* Wp = (const float*)d_in[4];
  const float* gain = (const float*)d_in[5];
  float* out = (float*)d_out;

  const int B = 2, S = 2048, D = 2048, H = 16, KH = 4;
  const int M = B * S;
  const int KVD = KH * 128;
  const int NQKV = D + 2 * KVD;  // 3072

  char* w = (char*)d_ws;
  u16* x_bf = (u16*)w;   w += (size_t)M * D * 2;
  u16* wqkv = (u16*)w;   w += (size_t)NQKV * D * 2;
  u16* wp_bf = (u16*)w;  w += (size_t)D * D * 2;
  u16* q_bf = (u16*)w;   w += (size_t)M * D * 2;
  u16* k_bf = (u16*)w;   w += (size_t)M * KVD * 2;
  u16* v_t = (u16*)w;    w += (size_t)M * KVD * 2;
  u16* ao_bf = (u16*)w;  w += (size_t)M * D * 2;
  float* cosT = (float*)w; w += (size_t)S * 64 * 4;
  float* sinT = (float*)w; w += (size_t)S * 64 * 4;
  if ((size_t)(w - (char*)d_ws) > ws_size) return;

  k_cast_bf16<<<(M * D / 4 + 255) / 256, 256, 0, stream>>>(x, x_bf, M * D / 4);
  {
    int na4 = D * D / 4, nb4 = KVD * D / 4, nc4 = KVD * D / 4, nd4 = D * D / 4;
    int tot = na4 + nb4 + nc4 + nd4;
    k_cast_w<<<(tot + 255) / 256, 256, 0, stream>>>(
        Wq, Wk, Wv, Wp, wqkv, wqkv + (size_t)D * D, wqkv + (size_t)(D + KVD) * D, wp_bf,
        na4, nb4, nc4, nd4);
  }

  double scale = (double)S / 1024.0;
  double base = (S > 1024) ? 10000.0 * pow(scale, 128.0 / 126.0) : 10000.0;
  float l2b = (float)(log(base) / log(2.0));
  k_rope_tab<<<S * 64 / 256, 256, 0, stream>>>(cosT, sinT, l2b);

  dim3 gqkv(NQKV / 384, M / 128);  // 8 x 32 = 256 blocks = 1/CU
  k_gemm_qkv8<<<gqkv, 512, 0, stream>>>(x_bf, wqkv, q_bf, k_bf, v_t, M, D);

  float qscale = 1.4426950408889634f / sqrtf(128.0f);
  k_rmsnorm_rope<<<(M * H) / 4, 256, 0, stream>>>(q_bf, cosT, sinT, gain, H, S, qscale);
  k_rmsnorm_rope<<<(M * KH) / 4, 256, 0, stream>>>(k_bf, cosT, sinT, nullptr, KH, S, 1.0f);

  dim3 blk(256);
  dim3 ga(B * H, S / 128);  // 512 blocks, paired q-tiles {y, 31-y}
  k_flash_attn<<<ga, blk, 0, stream>>>(q_bf, k_bf, v_t, ao_bf, S, H, KH, M);

  dim3 gp(D / 256, M / 128);  // 8 x 32 = 256 blocks = 1/CU
  k_gemm_bt8<<<gp, 512, 0, stream>>>(ao_bf, wp_bf, out, M, D, D);
}

// Round 15
// 207.378 us; speedup vs baseline: 1.1215x; 1.1215x over previous
//
#include <hip/hip_runtime.h>
#include <cmath>

typedef unsigned short u16;
typedef short v8s __attribute__((ext_vector_type(8)));
typedef float v4f __attribute__((ext_vector_type(4)));
typedef unsigned short v4u __attribute__((ext_vector_type(4)));
typedef unsigned int v2u __attribute__((ext_vector_type(2)));

__device__ __forceinline__ u16 f2bf(float f) {
  unsigned u = __builtin_bit_cast(unsigned, f);
  u += 0x7fffu + ((u >> 16) & 1u);
  return (u16)(u >> 16);
}
__device__ __forceinline__ float bf2f(u16 h) {
  unsigned u = ((unsigned)h) << 16;
  return __builtin_bit_cast(float, u);
}
// T12: hardware packed f32->bf16x2
__device__ __forceinline__ unsigned pk2(float a, float b) {
  unsigned r;
  asm("v_cvt_pk_bf16_f32 %0, %1, %2" : "=v"(r) : "v"(a), "v"(b));
  return r;
}

// ---------------- cast fp32 -> bf16 (vectorized, G13) ----------------
__global__ void k_cast_bf16(const float* __restrict__ in, u16* __restrict__ out, int n4) {
  int i = blockIdx.x * blockDim.x + threadIdx.x;
  if (i >= n4) return;
  v4f v = ((const v4f*)in)[i];
  v4u o;
  o[0] = f2bf(v[0]); o[1] = f2bf(v[1]); o[2] = f2bf(v[2]); o[3] = f2bf(v[3]);
  ((v4u*)out)[i] = o;
}

// ---------------- fused cast of the 4 weight tensors ----------------
__global__ void k_cast_w(const float* __restrict__ a, const float* __restrict__ b,
                         const float* __restrict__ c, const float* __restrict__ d,
                         u16* __restrict__ oa, u16* __restrict__ ob, u16* __restrict__ oc,
                         u16* __restrict__ od, int na4, int nb4, int nc4, int nd4) {
  int j = blockIdx.x * blockDim.x + threadIdx.x;
  const float* src;
  u16* dst;
  if (j < na4) { src = a; dst = oa; }
  else {
    j -= na4;
    if (j < nb4) { src = b; dst = ob; }
    else {
      j -= nb4;
      if (j < nc4) { src = c; dst = oc; }
      else {
        j -= nc4;
        if (j >= nd4) return;
        src = d; dst = od;
      }
    }
  }
  v4f v = ((const v4f*)src)[j];
  v4u o;
  o[0] = f2bf(v[0]); o[1] = f2bf(v[1]); o[2] = f2bf(v[2]); o[3] = f2bf(v[3]);
  ((v4u*)dst)[j] = o;
}

// ---------------- RoPE cos/sin table [S][64] f32 ----------------
__global__ void k_rope_tab(float* __restrict__ cosT, float* __restrict__ sinT, float log2_base) {
  int idx = blockIdx.x * blockDim.x + threadIdx.x;
  int t = idx >> 6, i = idx & 63;
  float inv = exp2f(-(float)i * (1.0f / 64.0f) * log2_base);
  float fr = (float)t * inv;
  cosT[idx] = cosf(fr);
  sinT[idx] = sinf(fr);
}

// ---- fused per-head RMSNorm + RoPE + gain for BOTH q and k (one launch) ----
// rows 0..MH-1 -> q (H=16, gain*qscale); rows MH..MH+MKH-1 -> k (KH=4, g=1)
__global__ void k_rmsnorm_rope2(u16* __restrict__ qb, u16* __restrict__ kb,
                                const float* __restrict__ cosT, const float* __restrict__ sinT,
                                const float* __restrict__ gain, int MH, int MKH, int S,
                                float qscale) {
  int idx = blockIdx.x * 4 + (threadIdx.x >> 6);
  int l = threadIdx.x & 63;
  u16* p;
  float g;
  int s;
  if (idx < MH) {
    p = qb + (size_t)idx * 128;
    g = qscale * gain[idx & 15];       // h = idx % 16
    s = (idx >> 4) & (S - 1);          // (idx/16) % S
  } else {
    int j = idx - MH;
    if (j >= MKH) return;
    p = kb + (size_t)j * 128;
    g = 1.0f;
    s = (j >> 2) & (S - 1);            // (j/4) % S
  }
  float a = bf2f(p[l]), b = bf2f(p[64 + l]);
  float ss = a * a + b * b;
#pragma unroll
  for (int o = 32; o; o >>= 1) ss += __shfl_xor(ss, o, 64);
  float r = rsqrtf(ss * (1.0f / 128.0f) + 1.1920929e-7f);
  a *= r; b *= r;
  float c = cosT[s * 64 + l], sn = sinT[s * 64 + l];
  p[l] = f2bf((a * c + b * sn) * g);
  p[64 + l] = f2bf((b * c - a * sn) * g);
}

// ======== 128x384 8-phase QKV GEMM (T1+T2+T3+T4+T5), BK=64, 512 thr =========
__device__ __forceinline__ void stage8(char* sL, const u16* __restrict__ Ag,
                                       const u16* __restrict__ Bg, int row0, int col0, int K,
                                       int n, int NT2, int tid) {
  int tile = n >> 2;
  if (tile >= NT2) return;
  int part = n & 3;  // 0:A-h0 1:B-h1 2:A-h1 3:B-h0
  int isB = part & 1;
  int half = (part == 1 || part == 2) ? 1 : 0;
  int k0 = tile * 64;
  if (!isB) {
    char* base = sL + (tile & 1) * 65536 + half * 8192;
    int o = tid * 16;
    int rowp = o >> 8;
    int un = (o & 255) ^ ((rowp & 15) << 4);
    int rsub = rowp + ((un >> 7) << 5);
    int k = (un & 127) >> 1;
    const u16* src = Ag + (size_t)(row0 + half * 64 + rsub) * K + (k0 + k);
    __builtin_amdgcn_global_load_lds((const __attribute__((address_space(1))) void*)src,
                                     (__attribute__((address_space(3))) void*)(base + o), 16, 0, 0);
  } else {
    char* base = sL + (tile & 1) * 65536 + 16384 + half * 24576;
#pragma unroll
    for (int j = 0; j < 3; ++j) {
      int o = (j * 512 + tid) * 16;
      int rowp = o >> 8;
      int un = (o & 255) ^ ((rowp & 15) << 4);
      int rsub = rowp + (un >> 7) * 96;
      int k = (un & 127) >> 1;
      const u16* src = Bg + (size_t)(col0 + half * 192 + rsub) * K + (k0 + k);
      __builtin_amdgcn_global_load_lds((const __attribute__((address_space(1))) void*)src,
                                       (__attribute__((address_space(3))) void*)(base + o), 16, 0,
                                       0);
    }
  }
}

#define PH(BUF, MH, NH, LA, LB, WAITC)                                                            \
  {                                                                                               \
    if (LA) {                                                                                     \
      _Pragma("unroll") for (int mi = 0; mi < 2; ++mi) {                                          \
        _Pragma("unroll") for (int c = 0; c < 2; ++c) {                                           \
          af[mi][c] = *(const v8s*)(sL + (BUF)*65536 + (MH)*8192 + (mi * 16 + lr) * 256 +         \
                                    ((wm * 128 + c * 64 + lh * 16) ^ (lr << 4)));                 \
        }                                                                                         \
      }                                                                                           \
    }                                                                                             \
    if (LB) {                                                                                     \
      _Pragma("unroll") for (int ni = 0; ni < 3; ++ni) {                                          \
        _Pragma("unroll") for (int c = 0; c < 2; ++c) {                                           \
          bf[ni][c] = *(const v8s*)(sL + (BUF)*65536 + 16384 + (NH)*24576 +                       \
                                    ((wn & 1) * 48 + ni * 16 + lr) * 256 +                        \
                                    (((wn >> 1) * 128 + c * 64 + lh * 16) ^ (lr << 4)));          \
        }                                                                                         \
      }                                                                                           \
    }                                                                                             \
    stage8(sL, Ag, Bg, row0, col0, K, n, NT2, tid);                                               \
    ++n;                                                                                          \
    if (WAITC) {                                                                                  \
      if (((n - 1) >> 2) < NT2) asm volatile("s_waitcnt vmcnt(4)" ::: "memory");                  \
      else asm volatile("s_waitcnt vmcnt(0)" ::: "memory");                                       \
    }                                                                                             \
    __builtin_amdgcn_sched_barrier(0);                                                            \
    __builtin_amdgcn_s_barrier();                                                                 \
    asm volatile("s_waitcnt lgkmcnt(0)" ::: "memory");                                            \
    __builtin_amdgcn_sched_barrier(0);                                                            \
    __builtin_amdgcn_s_setprio(1);                                                                \
    _Pragma("unroll") for (int mi = 0; mi < 2; ++mi) {                                            \
      _Pragma("unroll") for (int ni = 0; ni < 3; ++ni) {                                          \
        _Pragma("unroll") for (int c = 0; c < 2; ++c) {                                           \
          acc[(MH)*2 + mi][(NH)*3 + ni] = __builtin_amdgcn_mfma_f32_16x16x32_bf16(                \
              af[mi][c], bf[ni][c], acc[(MH)*2 + mi][(NH)*3 + ni], 0, 0, 0);                      \
        }                                                                                         \
      }                                                                                           \
    }                                                                                             \
    __builtin_amdgcn_s_setprio(0);                                                                \
    __builtin_amdgcn_sched_barrier(0);                                                            \
    __builtin_amdgcn_s_barrier();                                                                 \
  }

__global__ __launch_bounds__(512, 2) void k_gemm_qkv8(const u16* __restrict__ Ag,
                                                      const u16* __restrict__ Bg,
                                                      u16* __restrict__ q_o, u16* __restrict__ k_o,
                                                      u16* __restrict__ v_o, int M, int K) {
  __shared__ char sL[131072];
  const int tid = threadIdx.x;
  const int wid = tid >> 6, l = tid & 63;
  const int lr = l & 15, lh = l >> 4;
  const int wm = wid >> 2, wn = wid & 3;
  const int nwg = gridDim.x * gridDim.y;
  const int bid = blockIdx.y * gridDim.x + blockIdx.x;
  const int cpx = nwg >> 3;
  const int swz = (bid & 7) * cpx + (bid >> 3);
  const int row0 = (swz / gridDim.x) * 128, col0 = (swz % gridDim.x) * 384;
  const int NT2 = K >> 6;

  v4f zz = {0.f, 0.f, 0.f, 0.f};
  v4f acc[4][6];
#pragma unroll
  for (int i = 0; i < 4; ++i)
#pragma unroll
    for (int j = 0; j < 6; ++j) acc[i][j] = zz;
  v8s af[2][2], bf[3][2];

  for (int i = 0; i < 6; ++i) stage8(sL, Ag, Bg, row0, col0, K, i, NT2, tid);
  asm volatile("s_waitcnt vmcnt(4)" ::: "memory");
  __builtin_amdgcn_sched_barrier(0);
  __builtin_amdgcn_s_barrier();

  int n = 6;
  for (int it = 0; it < NT2 / 2; ++it) {
    PH(0, 0, 0, 1, 1, 0)
    PH(0, 0, 1, 0, 1, 0)
    PH(0, 1, 1, 1, 0, 0)
    PH(0, 1, 0, 0, 1, 1)
    PH(1, 0, 0, 1, 1, 0)
    PH(1, 0, 1, 0, 1, 0)
    PH(1, 1, 1, 1, 0, 0)
    PH(1, 1, 0, 0, 1, 1)
  }

#pragma unroll
  for (int MH = 0; MH < 2; ++MH) {
#pragma unroll
    for (int mi = 0; mi < 2; ++mi) {
#pragma unroll
      for (int NH = 0; NH < 2; ++NH) {
#pragma unroll
        for (int ni = 0; ni < 3; ++ni) {
          int row = row0 + MH * 64 + wm * 32 + mi * 16 + lh * 4;
          int col = col0 + NH * 192 + wn * 48 + ni * 16 + lr;
          v4f a_ = acc[MH * 2 + mi][NH * 3 + ni];
          if (col < 2048) {
#pragma unroll
            for (int r = 0; r < 4; ++r) q_o[(size_t)(row + r) * 2048 + col] = f2bf(a_[r]);
          } else if (col < 2560) {
#pragma unroll
            for (int r = 0; r < 4; ++r) k_o[(size_t)(row + r) * 512 + (col - 2048)] = f2bf(a_[r]);
          } else {
#pragma unroll
            for (int r = 0; r < 4; ++r) v_o[(size_t)(col - 2560) * M + row + r] = f2bf(a_[r]);
          }
        }
      }
    }
  }
}

// ======== 128x256 8-phase out-proj GEMM (f32 C), BK=64, 512 thr =========
__device__ __forceinline__ void stage8b(char* sL, const u16* __restrict__ Ag,
                                        const u16* __restrict__ Bg, int row0, int col0, int K,
                                        int n, int NT2, int tid) {
  int tile = n >> 2;
  if (tile >= NT2) return;
  int part = n & 3;
  int isB = part & 1;
  int half = (part == 1 || part == 2) ? 1 : 0;
  int k0 = tile * 64;
  if (!isB) {
    char* base = sL + (tile & 1) * 49152 + half * 8192;
    int o = tid * 16;
    int rowp = o >> 8;
    int un = (o & 255) ^ ((rowp & 15) << 4);
    int rsub = rowp + ((un >> 7) << 5);
    int k = (un & 127) >> 1;
    const u16* src = Ag + (size_t)(row0 + half * 64 + rsub) * K + (k0 + k);
    __builtin_amdgcn_global_load_lds((const __attribute__((address_space(1))) void*)src,
                                     (__attribute__((address_space(3))) void*)(base + o), 16, 0, 0);
  } else {
    char* base = sL + (tile & 1) * 49152 + 16384 + half * 16384;
#pragma unroll
    for (int j = 0; j < 2; ++j) {
      int o = (j * 512 + tid) * 16;
      int rowp = o >> 8;
      int un = (o & 255) ^ ((rowp & 15) << 4);
      int rsub = rowp + (un >> 7) * 64;
      int k = (un & 127) >> 1;
      const u16* src = Bg + (size_t)(col0 + half * 128 + rsub) * K + (k0 + k);
      __builtin_amdgcn_global_load_lds((const __attribute__((address_space(1))) void*)src,
                                       (__attribute__((address_space(3))) void*)(base + o), 16, 0,
                                       0);
    }
  }
}

#define PH2(BUF, MH, NH, LA, LB, WAITC)                                                           \
  {                                                                                               \
    if (LA) {                                                                                     \
      _Pragma("unroll") for (int mi = 0; mi < 2; ++mi) {                                          \
        _Pragma("unroll") for (int c = 0; c < 2; ++c) {                                           \
          af[mi][c] = *(const v8s*)(sL + (BUF)*49152 + (MH)*8192 + (mi * 16 + lr) * 256 +         \
                                    ((wm * 128 + c * 64 + lh * 16) ^ (lr << 4)));                 \
        }                                                                                         \
      }                                                                                           \
    }                                                                                             \
    if (LB) {                                                                                     \
      _Pragma("unroll") for (int ni = 0; ni < 2; ++ni) {                                          \
        _Pragma("unroll") for (int c = 0; c < 2; ++c) {                                           \
          bf[ni][c] = *(const v8s*)(sL + (BUF)*49152 + 16384 + (NH)*16384 +                       \
                                    ((wn & 1) * 32 + ni * 16 + lr) * 256 +                        \
                                    (((wn >> 1) * 128 + c * 64 + lh * 16) ^ (lr << 4)));          \
        }                                                                                         \
      }                                                                                           \
    }                                                                                             \
    stage8b(sL, Ag, Bg, row0, col0, K, n, NT2, tid);                                              \
    ++n;                                                                                          \
    if (WAITC) {                                                                                  \
      if (((n - 1) >> 2) < NT2) asm volatile("s_waitcnt vmcnt(3)" ::: "memory");                  \
      else asm volatile("s_waitcnt vmcnt(0)" ::: "memory");                                       \
    }                                                                                             \
    __builtin_amdgcn_sched_barrier(0);                                                            \
    __builtin_amdgcn_s_barrier();                                                                 \
    asm volatile("s_waitcnt lgkmcnt(0)" ::: "memory");                                            \
    __builtin_amdgcn_sched_barrier(0);                                                            \
    __builtin_amdgcn_s_setprio(1);                                                                \
    _Pragma("unroll") for (int mi = 0; mi < 2; ++mi) {                                            \
      _Pragma("unroll") for (int ni = 0; ni < 2; ++ni) {                                          \
        _Pragma("unroll") for (int c = 0; c < 2; ++c) {                                           \
          acc[(MH)*2 + mi][(NH)*2 + ni] = __builtin_amdgcn_mfma_f32_16x16x32_bf16(                \
              af[mi][c], bf[ni][c], acc[(MH)*2 + mi][(NH)*2 + ni], 0, 0, 0);                      \
        }                                                                                         \
      }                                                                                           \
    }                                                                                             \
    __builtin_amdgcn_s_setprio(0);                                                                \
    __builtin_amdgcn_sched_barrier(0);                                                            \
    __builtin_amdgcn_s_barrier();                                                                 \
  }

__global__ __launch_bounds__(512, 2) void k_gemm_bt8(const u16* __restrict__ Ag,
                                                     const u16* __restrict__ Bg,
                                                     float* __restrict__ C, int M, int N, int K) {
  __shared__ char sL[98304];
  const int tid = threadIdx.x;
  const int wid = tid >> 6, l = tid & 63;
  const int lr = l & 15, lh = l >> 4;
  const int wm = wid >> 2, wn = wid & 3;
  const int nwg = gridDim.x * gridDim.y;
  const int bid = blockIdx.y * gridDim.x + blockIdx.x;
  const int cpx = nwg >> 3;
  const int swz = (bid & 7) * cpx + (bid >> 3);
  const int row0 = (swz / gridDim.x) * 128, col0 = (swz % gridDim.x) * 256;
  const int NT2 = K >> 6;

  v4f zz = {0.f, 0.f, 0.f, 0.f};
  v4f acc[4][4];
#pragma unroll
  for (int i = 0; i < 4; ++i)
#pragma unroll
    for (int j = 0; j < 4; ++j) acc[i][j] = zz;
  v8s af[2][2], bf[2][2];

  for (int i = 0; i < 6; ++i) stage8b(sL, Ag, Bg, row0, col0, K, i, NT2, tid);
  asm volatile("s_waitcnt vmcnt(3)" ::: "memory");
  __builtin_amdgcn_sched_barrier(0);
  __builtin_amdgcn_s_barrier();

  int n = 6;
  for (int it = 0; it < NT2 / 2; ++it) {
    PH2(0, 0, 0, 1, 1, 0)
    PH2(0, 0, 1, 0, 1, 0)
    PH2(0, 1, 1, 1, 0, 0)
    PH2(0, 1, 0, 0, 1, 1)
    PH2(1, 0, 0, 1, 1, 0)
    PH2(1, 0, 1, 0, 1, 0)
    PH2(1, 1, 1, 1, 0, 0)
    PH2(1, 1, 0, 0, 1, 1)
  }

#pragma unroll
  for (int MH = 0; MH < 2; ++MH) {
#pragma unroll
    for (int mi = 0; mi < 2; ++mi) {
#pragma unroll
      for (int NH = 0; NH < 2; ++NH) {
#pragma unroll
        for (int ni = 0; ni < 2; ++ni) {
          int row = row0 + MH * 64 + wm * 32 + mi * 16 + lh * 4;
          int col = col0 + NH * 128 + (wn & 1) * 32 + (wn >> 1) * 64 + ni * 16 + lr;
          v4f a_ = acc[MH * 2 + mi][NH * 2 + ni];
#pragma unroll
          for (int r = 0; r < 4; ++r) C[(size_t)(row + r) * N + col] = a_[r];
        }
      }
    }
  }
}

// ------- causal GQA flash attention v13: R13 structure + stage-at-top -------
// KVBLK=64, K+V double-buffered in LDS (72KB, 2 blocks/CU), paired schedule.
__global__ __launch_bounds__(256) void k_flash_attn(const u16* __restrict__ Q,
                                                    const u16* __restrict__ Kb,
                                                    const u16* __restrict__ Vt,
                                                    u16* __restrict__ O, int S, int H, int KH,
                                                    int Mtot) {
  const int bh = blockIdx.x;
  const int h = bh % H, b = bh / H;
  const int kvh = h / (H / KH);
  const int w = threadIdx.x >> 6, l = threadIdx.x & 63;
  const int lr = l & 15, lh = l >> 4;

  __shared__ alignas(16) char sK[2][16384];
  __shared__ alignas(16) char sV[2][16384];
  __shared__ alignas(16) unsigned P_lds[4][16 * 32];
  unsigned* prow = P_lds[w] + lr * 32;
  const int xr = (lr & 7) << 2;

  v4f zz = {0.f, 0.f, 0.f, 0.f};
  const int strideK = KH * 128;
  const int strideKB = strideK * 2;
  const char* KheadB = (const char*)Kb + 2 * ((size_t)b * S * strideK + (size_t)kvh * 128);
  const char* VheadB = (const char*)Vt + 2 * ((size_t)(kvh * 128) * Mtot + (size_t)b * S);
  const size_t MtotB = (size_t)Mtot * 2;

  auto stage = [&](int kv0, int bufi) {
    const char* Kt = KheadB + (size_t)kv0 * strideKB;
#pragma unroll
    for (int j = 0; j < 4; ++j) {
      int jj = w * 4 + j;
      int ci = jj * 64 + l;
      int r = ci >> 4;
      int bc = (ci & 15) << 4;
      const char* src = Kt + (size_t)r * strideKB + (bc ^ ((r & 15) << 4));
      __builtin_amdgcn_global_load_lds((const __attribute__((address_space(1))) void*)src,
                                       (__attribute__((address_space(3))) void*)(sK[bufi] + jj * 1024),
                                       16, 0, 0);
    }
    const char* Vt0 = VheadB + (size_t)kv0 * 2;
#pragma unroll
    for (int j = 0; j < 4; ++j) {
      int jj = w * 4 + j;
      int ci = jj * 64 + l;
      int r = ci >> 3;
      int bc = (ci & 7) << 4;
      const char* src = Vt0 + (size_t)r * MtotB + (bc ^ ((r & 7) << 4));
      __builtin_amdgcn_global_load_lds((const __attribute__((address_space(1))) void*)src,
                                       (__attribute__((address_space(3))) void*)(sV[bufi] + jj * 1024),
                                       16, 0, 0);
    }
  };

  for (int pp = 0; pp < 2; ++pp) {
    const int qt = (pp == 0) ? (int)blockIdx.y : (S / 64 - 1 - (int)blockIdx.y);
    const int q0 = qt * 64;
    const int nt = qt + 1;
    const int qi = q0 + w * 16 + lr;

    v8s qf[4];
    const u16* qp = Q + (size_t)(b * S + q0 + w * 16 + lr) * (size_t)(H * 128) + h * 128 + lh * 8;
#pragma unroll
    for (int c = 0; c < 4; ++c) qf[c] = *(const v8s*)(qp + c * 32);

    v4f o_acc[8];
#pragma unroll
    for (int df = 0; df < 8; ++df) o_acc[df] = zz;
    float m_run = -1e30f, l_run = 0.f;

    stage(0, 0);
    __syncthreads();

    int buf = 0;
    for (int t = 0; t < nt; ++t) {
      const int kv0 = t * 64;
      const bool lastTile = (t == nt - 1);
      const char* sKb = sK[buf];
      const char* sVb = sV[buf];

      // ---- stage next tile FIRST (widest issue->drain window) ----
      if (t + 1 < nt) stage(kv0 + 64, buf ^ 1);

      // ---- QK^T swapped (C rows=kv, cols=q), K from LDS ----
      v4f sv[4];
      __builtin_amdgcn_s_setprio(1);
#pragma unroll
      for (int nf = 0; nf < 4; ++nf) {
        v4f a_ = zz;
        const int r = nf * 16 + lr;
#pragma unroll
        for (int c = 0; c < 4; ++c) {
          v8s kf = *(const v8s*)(sKb + r * 256 + ((lh * 16 + c * 64) ^ (lr << 4)));
          a_ = __builtin_amdgcn_mfma_f32_16x16x32_bf16(kf, qf[c], a_, 0, 0, 0);
        }
        sv[nf] = a_;
      }
      __builtin_amdgcn_s_setprio(0);

      if (lastTile) {
#pragma unroll
        for (int nf = 0; nf < 4; ++nf)
#pragma unroll
          for (int r = 0; r < 4; ++r)
            if (kv0 + nf * 16 + lh * 4 + r > qi) sv[nf][r] = -1e30f;
      }
      float pm0 = fmaxf(fmaxf(sv[0][0], sv[0][1]), fmaxf(sv[0][2], sv[0][3]));
      float pm1 = fmaxf(fmaxf(sv[1][0], sv[1][1]), fmaxf(sv[1][2], sv[1][3]));
      float pm2 = fmaxf(fmaxf(sv[2][0], sv[2][1]), fmaxf(sv[2][2], sv[2][3]));
      float pm3 = fmaxf(fmaxf(sv[3][0], sv[3][1]), fmaxf(sv[3][2], sv[3][3]));
      float pmax = fmaxf(fmaxf(pm0, pm1), fmaxf(pm2, pm3));
      pmax = fmaxf(pmax, __shfl_xor(pmax, 16, 64));
      pmax = fmaxf(pmax, __shfl_xor(pmax, 32, 64));
      if (!__all(pmax - m_run <= 8.0f)) {  // T13 defer-max
        float mnew = fmaxf(m_run, pmax);
        float corr = exp2f(m_run - mnew);
        l_run *= corr;
        m_run = mnew;
        float corrq[4];
#pragma unroll
        for (int r = 0; r < 4; ++r) corrq[r] = __shfl(corr, lh * 4 + r, 16);
#pragma unroll
        for (int df = 0; df < 8; ++df)
#pragma unroll
          for (int r = 0; r < 4; ++r) o_acc[df][r] *= corrq[r];
      }
      float rsum = 0.f;
#pragma unroll
      for (int nf = 0; nf < 4; ++nf)
#pragma unroll
        for (int r = 0; r < 4; ++r) {
          float pv = exp2f(sv[nf][r] - m_run);
          sv[nf][r] = pv;
          rsum += pv;
        }
      rsum += __shfl_xor(rsum, 16, 64);
      rsum += __shfl_xor(rsum, 32, 64);
      l_run += rsum;

#pragma unroll
      for (int nf = 0; nf < 4; ++nf) {
        v2u pw;
        pw[0] = pk2(sv[nf][0], sv[nf][1]);
        pw[1] = pk2(sv[nf][2], sv[nf][3]);
        *(v2u*)(prow + ((nf * 8 + lh * 2) ^ xr)) = pw;
      }
      asm volatile("s_waitcnt lgkmcnt(0)" ::: "memory");
      __builtin_amdgcn_sched_barrier(0);  // rule 18
      v8s ap[2];
#pragma unroll
      for (int c2 = 0; c2 < 2; ++c2) ap[c2] = *(const v8s*)(prow + ((c2 * 16 + lh * 4) ^ xr));

      __builtin_amdgcn_s_setprio(1);
#pragma unroll
      for (int df = 0; df < 8; ++df) {
        const int r = df * 16 + lr;
        const char* vrow = sVb + r * 128;
        const int key = (lr & 7) << 4;
#pragma unroll
        for (int c2 = 0; c2 < 2; ++c2) {
          v8s vf = *(const v8s*)(vrow + ((lh * 16 + c2 * 64) ^ key));
          o_acc[df] = __builtin_amdgcn_mfma_f32_16x16x32_bf16(ap[c2], vf, o_acc[df], 0, 0, 0);
        }
      }
      __builtin_amdgcn_s_setprio(0);

      __syncthreads();
      buf ^= 1;
    }

    float rl = 1.0f / l_run;
    float invq[4];
#pragma unroll
    for (int r = 0; r < 4; ++r) invq[r] = __shfl(rl, lh * 4 + r, 16);
    u16* op = O + (size_t)(b * S + q0 + w * 16 + lh * 4) * (size_t)(H * 128) + h * 128;
#pragma unroll
    for (int r = 0; r < 4; ++r)
#pragma unroll
      for (int df = 0; df < 8; ++df)
        op[(size_t)r * (H * 128) + df * 16 + lr] = f2bf(o_acc[df][r] * invq[r]);
  }
}

extern "C" void kernel_launch(void* const* d_in, const int* in_sizes, int n_in, void* d_out,
                              int out_size, void* d_ws, size_t ws_size, hipStream_t stream) {
  const float* x = (const float*)d_in[0];
  const float* Wq = (const float*)d_in[1];
  const float* Wk = (const float*)d_in[2];
  const float* Wv = (const float*)d_in[3];
  const float* Wp = (const float*)d_in[4];
  const float* gain = (const float*)d_in[5];
  float* out = (float*)d_out;

  const int B = 2, S = 2048, D = 2048, H = 16, KH = 4;
  const int M = B * S;
  const int KVD = KH * 128;
  const int NQKV = D + 2 * KVD;  // 3072

  char* w = (char*)d_ws;
  u16* x_bf = (u16*)w;   w += (size_t)M * D * 2;
  u16* wqkv = (u16*)w;   w += (size_t)NQKV * D * 2;
  u16* wp_bf = (u16*)w;  w += (size_t)D * D * 2;
  u16* q_bf = (u16*)w;   w += (size_t)M * D * 2;
  u16* k_bf = (u16*)w;   w += (size_t)M * KVD * 2;
  u16* v_t = (u16*)w;    w += (size_t)M * KVD * 2;
  u16* ao_bf = (u16*)w;  w += (size_t)M * D * 2;
  float* cosT = (float*)w; w += (size_t)S * 64 * 4;
  float* sinT = (float*)w; w += (size_t)S * 64 * 4;
  if ((size_t)(w - (char*)d_ws) > ws_size) return;

  k_cast_bf16<<<(M * D / 4 + 255) / 256, 256, 0, stream>>>(x, x_bf, M * D / 4);
  {
    int na4 = D * D / 4, nb4 = KVD * D / 4, nc4 = KVD * D / 4, nd4 = D * D / 4;
    int tot = na4 + nb4 + nc4 + nd4;
    k_cast_w<<<(tot + 255) / 256, 256, 0, stream>>>(
        Wq, Wk, Wv, Wp, wqkv, wqkv + (size_t)D * D, wqkv + (size_t)(D + KVD) * D, wp_bf,
        na4, nb4, nc4, nd4);
  }

  double scale = (double)S / 1024.0;
  double base = (S > 1024) ? 10000.0 * pow(scale, 128.0 / 126.0) : 10000.0;
  float l2b = (float)(log(base) / log(2.0));
  k_rope_tab<<<S * 64 / 256, 256, 0, stream>>>(cosT, sinT, l2b);

  dim3 gqkv(NQKV / 384, M / 128);  // 8 x 32 = 256 blocks = 1/CU
  k_gemm_qkv8<<<gqkv, 512, 0, stream>>>(x_bf, wqkv, q_bf, k_bf, v_t, M, D);

  float qscale = 1.4426950408889634f / sqrtf(128.0f);
  {
    int MH_ = M * H, MKH_ = M * KH;
    int rows = MH_ + MKH_;
    k_rmsnorm_rope2<<<rows / 4, 256, 0, stream>>>(q_bf, k_bf, cosT, sinT, gain, MH_, MKH_, S,
                                                  qscale);
  }

  dim3 blk(256);
  dim3 ga(B * H, S / 128);  // 512 blocks, paired q-tiles {y, 31-y}
  k_flash_attn<<<ga, blk, 0, stream>>>(q_bf, k_bf, v_t, ao_bf, S, H, KH, M);

  dim3 gp(D / 256, M / 128);  // 8 x 32 = 256 blocks = 1/CU
  k_gemm_bt8<<<gp, 512, 0, stream>>>(ao_bf, wp_bf, out, M, D, D);
}

// Round 16
// 204.283 us; speedup vs baseline: 1.1385x; 1.0152x over previous
//
#include <hip/hip_runtime.h>
#include <cmath>

typedef unsigned short u16;
typedef short v8s __attribute__((ext_vector_type(8)));
typedef float v4f __attribute__((ext_vector_type(4)));
typedef unsigned short v4u __attribute__((ext_vector_type(4)));
typedef unsigned int v2u __attribute__((ext_vector_type(2)));

__device__ __forceinline__ u16 f2bf(float f) {
  unsigned u = __builtin_bit_cast(unsigned, f);
  u += 0x7fffu + ((u >> 16) & 1u);
  return (u16)(u >> 16);
}
__device__ __forceinline__ float bf2f(u16 h) {
  unsigned u = ((unsigned)h) << 16;
  return __builtin_bit_cast(float, u);
}
// T12: hardware packed f32->bf16x2
__device__ __forceinline__ unsigned pk2(float a, float b) {
  unsigned r;
  asm("v_cvt_pk_bf16_f32 %0, %1, %2" : "=v"(r) : "v"(a), "v"(b));
  return r;
}

// ---------------- cast fp32 -> bf16 (vectorized, G13) ----------------
__global__ void k_cast_bf16(const float* __restrict__ in, u16* __restrict__ out, int n4) {
  int i = blockIdx.x * blockDim.x + threadIdx.x;
  if (i >= n4) return;
  v4f v = ((const v4f*)in)[i];
  v4u o;
  o[0] = f2bf(v[0]); o[1] = f2bf(v[1]); o[2] = f2bf(v[2]); o[3] = f2bf(v[3]);
  ((v4u*)out)[i] = o;
}

// ---------------- fused cast of the 4 weight tensors ----------------
__global__ void k_cast_w(const float* __restrict__ a, const float* __restrict__ b,
                         const float* __restrict__ c, const float* __restrict__ d,
                         u16* __restrict__ oa, u16* __restrict__ ob, u16* __restrict__ oc,
                         u16* __restrict__ od, int na4, int nb4, int nc4, int nd4) {
  int j = blockIdx.x * blockDim.x + threadIdx.x;
  const float* src;
  u16* dst;
  if (j < na4) { src = a; dst = oa; }
  else {
    j -= na4;
    if (j < nb4) { src = b; dst = ob; }
    else {
      j -= nb4;
      if (j < nc4) { src = c; dst = oc; }
      else {
        j -= nc4;
        if (j >= nd4) return;
        src = d; dst = od;
      }
    }
  }
  v4f v = ((const v4f*)src)[j];
  v4u o;
  o[0] = f2bf(v[0]); o[1] = f2bf(v[1]); o[2] = f2bf(v[2]); o[3] = f2bf(v[3]);
  ((v4u*)dst)[j] = o;
}

// ---------------- RoPE cos/sin table [S][64] f32 ----------------
__global__ void k_rope_tab(float* __restrict__ cosT, float* __restrict__ sinT, float log2_base) {
  int idx = blockIdx.x * blockDim.x + threadIdx.x;
  int t = idx >> 6, i = idx & 63;
  float inv = exp2f(-(float)i * (1.0f / 64.0f) * log2_base);
  float fr = (float)t * inv;
  cosT[idx] = cosf(fr);
  sinT[idx] = sinf(fr);
}

// ---- fused per-head RMSNorm + RoPE + gain for BOTH q and k (one launch) ----
__global__ void k_rmsnorm_rope2(u16* __restrict__ qb, u16* __restrict__ kb,
                                const float* __restrict__ cosT, const float* __restrict__ sinT,
                                const float* __restrict__ gain, int MH, int MKH, int S,
                                float qscale) {
  int idx = blockIdx.x * 4 + (threadIdx.x >> 6);
  int l = threadIdx.x & 63;
  u16* p;
  float g;
  int s;
  if (idx < MH) {
    p = qb + (size_t)idx * 128;
    g = qscale * gain[idx & 15];
    s = (idx >> 4) & (S - 1);
  } else {
    int j = idx - MH;
    if (j >= MKH) return;
    p = kb + (size_t)j * 128;
    g = 1.0f;
    s = (j >> 2) & (S - 1);
  }
  float a = bf2f(p[l]), b = bf2f(p[64 + l]);
  float ss = a * a + b * b;
#pragma unroll
  for (int o = 32; o; o >>= 1) ss += __shfl_xor(ss, o, 64);
  float r = rsqrtf(ss * (1.0f / 128.0f) + 1.1920929e-7f);
  a *= r; b *= r;
  float c = cosT[s * 64 + l], sn = sinT[s * 64 + l];
  p[l] = f2bf((a * c + b * sn) * g);
  p[64 + l] = f2bf((b * c - a * sn) * g);
}

// ======== 128x384 8-phase QKV GEMM (T1+T2+T3+T4+T5), BK=64, 512 thr =========
__device__ __forceinline__ void stage8(char* sL, const u16* __restrict__ Ag,
                                       const u16* __restrict__ Bg, int row0, int col0, int K,
                                       int n, int NT2, int tid) {
  int tile = n >> 2;
  if (tile >= NT2) return;
  int part = n & 3;  // 0:A-h0 1:B-h1 2:A-h1 3:B-h0
  int isB = part & 1;
  int half = (part == 1 || part == 2) ? 1 : 0;
  int k0 = tile * 64;
  if (!isB) {
    char* base = sL + (tile & 1) * 65536 + half * 8192;
    int o = tid * 16;
    int rowp = o >> 8;
    int un = (o & 255) ^ ((rowp & 15) << 4);
    int rsub = rowp + ((un >> 7) << 5);
    int k = (un & 127) >> 1;
    const u16* src = Ag + (size_t)(row0 + half * 64 + rsub) * K + (k0 + k);
    __builtin_amdgcn_global_load_lds((const __attribute__((address_space(1))) void*)src,
                                     (__attribute__((address_space(3))) void*)(base + o), 16, 0, 0);
  } else {
    char* base = sL + (tile & 1) * 65536 + 16384 + half * 24576;
#pragma unroll
    for (int j = 0; j < 3; ++j) {
      int o = (j * 512 + tid) * 16;
      int rowp = o >> 8;
      int un = (o & 255) ^ ((rowp & 15) << 4);
      int rsub = rowp + (un >> 7) * 96;
      int k = (un & 127) >> 1;
      const u16* src = Bg + (size_t)(col0 + half * 192 + rsub) * K + (k0 + k);
      __builtin_amdgcn_global_load_lds((const __attribute__((address_space(1))) void*)src,
                                       (__attribute__((address_space(3))) void*)(base + o), 16, 0,
                                       0);
    }
  }
}

#define PH(BUF, MH, NH, LA, LB, WAITC)                                                            \
  {                                                                                               \
    if (LA) {                                                                                     \
      _Pragma("unroll") for (int mi = 0; mi < 2; ++mi) {                                          \
        _Pragma("unroll") for (int c = 0; c < 2; ++c) {                                           \
          af[mi][c] = *(const v8s*)(sL + (BUF)*65536 + (MH)*8192 + (mi * 16 + lr) * 256 +         \
                                    ((wm * 128 + c * 64 + lh * 16) ^ (lr << 4)));                 \
        }                                                                                         \
      }                                                                                           \
    }                                                                                             \
    if (LB) {                                                                                     \
      _Pragma("unroll") for (int ni = 0; ni < 3; ++ni) {                                          \
        _Pragma("unroll") for (int c = 0; c < 2; ++c) {                                           \
          bf[ni][c] = *(const v8s*)(sL + (BUF)*65536 + 16384 + (NH)*24576 +                       \
                                    ((wn & 1) * 48 + ni * 16 + lr) * 256 +                        \
                                    (((wn >> 1) * 128 + c * 64 + lh * 16) ^ (lr << 4)));          \
        }                                                                                         \
      }                                                                                           \
    }                                                                                             \
    stage8(sL, Ag, Bg, row0, col0, K, n, NT2, tid);                                               \
    ++n;                                                                                          \
    if (WAITC) {                                                                                  \
      if (((n - 1) >> 2) < NT2) asm volatile("s_waitcnt vmcnt(4)" ::: "memory");                  \
      else asm volatile("s_waitcnt vmcnt(0)" ::: "memory");                                       \
    }                                                                                             \
    __builtin_amdgcn_sched_barrier(0);                                                            \
    __builtin_amdgcn_s_barrier();                                                                 \
    asm volatile("s_waitcnt lgkmcnt(0)" ::: "memory");                                            \
    __builtin_amdgcn_sched_barrier(0);                                                            \
    __builtin_amdgcn_s_setprio(1);                                                                \
    _Pragma("unroll") for (int mi = 0; mi < 2; ++mi) {                                            \
      _Pragma("unroll") for (int ni = 0; ni < 3; ++ni) {                                          \
        _Pragma("unroll") for (int c = 0; c < 2; ++c) {                                           \
          acc[(MH)*2 + mi][(NH)*3 + ni] = __builtin_amdgcn_mfma_f32_16x16x32_bf16(                \
              af[mi][c], bf[ni][c], acc[(MH)*2 + mi][(NH)*3 + ni], 0, 0, 0);                      \
        }                                                                                         \
      }                                                                                           \
    }                                                                                             \
    __builtin_amdgcn_s_setprio(0);                                                                \
    __builtin_amdgcn_sched_barrier(0);                                                            \
    __builtin_amdgcn_s_barrier();                                                                 \
  }

__global__ __launch_bounds__(512, 2) void k_gemm_qkv8(const u16* __restrict__ Ag,
                                                      const u16* __restrict__ Bg,
                                                      u16* __restrict__ q_o, u16* __restrict__ k_o,
                                                      u16* __restrict__ v_o, int M, int K) {
  __shared__ char sL[131072];
  const int tid = threadIdx.x;
  const int wid = tid >> 6, l = tid & 63;
  const int lr = l & 15, lh = l >> 4;
  const int wm = wid >> 2, wn = wid & 3;
  const int nwg = gridDim.x * gridDim.y;
  const int bid = blockIdx.y * gridDim.x + blockIdx.x;
  const int cpx = nwg >> 3;
  const int swz = (bid & 7) * cpx + (bid >> 3);
  const int row0 = (swz / gridDim.x) * 128, col0 = (swz % gridDim.x) * 384;
  const int NT2 = K >> 6;

  v4f zz = {0.f, 0.f, 0.f, 0.f};
  v4f acc[4][6];
#pragma unroll
  for (int i = 0; i < 4; ++i)
#pragma unroll
    for (int j = 0; j < 6; ++j) acc[i][j] = zz;
  v8s af[2][2], bf[3][2];

  for (int i = 0; i < 6; ++i) stage8(sL, Ag, Bg, row0, col0, K, i, NT2, tid);
  asm volatile("s_waitcnt vmcnt(4)" ::: "memory");
  __builtin_amdgcn_sched_barrier(0);
  __builtin_amdgcn_s_barrier();

  int n = 6;
  for (int it = 0; it < NT2 / 2; ++it) {
    PH(0, 0, 0, 1, 1, 0)
    PH(0, 0, 1, 0, 1, 0)
    PH(0, 1, 1, 1, 0, 0)
    PH(0, 1, 0, 0, 1, 1)
    PH(1, 0, 0, 1, 1, 0)
    PH(1, 0, 1, 0, 1, 0)
    PH(1, 1, 1, 1, 0, 0)
    PH(1, 1, 0, 0, 1, 1)
  }

#pragma unroll
  for (int MH = 0; MH < 2; ++MH) {
#pragma unroll
    for (int mi = 0; mi < 2; ++mi) {
#pragma unroll
      for (int NH = 0; NH < 2; ++NH) {
#pragma unroll
        for (int ni = 0; ni < 3; ++ni) {
          int row = row0 + MH * 64 + wm * 32 + mi * 16 + lh * 4;
          int col = col0 + NH * 192 + wn * 48 + ni * 16 + lr;
          v4f a_ = acc[MH * 2 + mi][NH * 3 + ni];
          if (col < 2048) {
#pragma unroll
            for (int r = 0; r < 4; ++r) q_o[(size_t)(row + r) * 2048 + col] = f2bf(a_[r]);
          } else if (col < 2560) {
#pragma unroll
            for (int r = 0; r < 4; ++r) k_o[(size_t)(row + r) * 512 + (col - 2048)] = f2bf(a_[r]);
          } else {
#pragma unroll
            for (int r = 0; r < 4; ++r) v_o[(size_t)(col - 2560) * M + row + r] = f2bf(a_[r]);
          }
        }
      }
    }
  }
}

// ======== 128x256 8-phase out-proj GEMM (f32 C), BK=64, 512 thr =========
__device__ __forceinline__ void stage8b(char* sL, const u16* __restrict__ Ag,
                                        const u16* __restrict__ Bg, int row0, int col0, int K,
                                        int n, int NT2, int tid) {
  int tile = n >> 2;
  if (tile >= NT2) return;
  int part = n & 3;
  int isB = part & 1;
  int half = (part == 1 || part == 2) ? 1 : 0;
  int k0 = tile * 64;
  if (!isB) {
    char* base = sL + (tile & 1) * 49152 + half * 8192;
    int o = tid * 16;
    int rowp = o >> 8;
    int un = (o & 255) ^ ((rowp & 15) << 4);
    int rsub = rowp + ((un >> 7) << 5);
    int k = (un & 127) >> 1;
    const u16* src = Ag + (size_t)(row0 + half * 64 + rsub) * K + (k0 + k);
    __builtin_amdgcn_global_load_lds((const __attribute__((address_space(1))) void*)src,
                                     (__attribute__((address_space(3))) void*)(base + o), 16, 0, 0);
  } else {
    char* base = sL + (tile & 1) * 49152 + 16384 + half * 16384;
#pragma unroll
    for (int j = 0; j < 2; ++j) {
      int o = (j * 512 + tid) * 16;
      int rowp = o >> 8;
      int un = (o & 255) ^ ((rowp & 15) << 4);
      int rsub = rowp + (un >> 7) * 64;
      int k = (un & 127) >> 1;
      const u16* src = Bg + (size_t)(col0 + half * 128 + rsub) * K + (k0 + k);
      __builtin_amdgcn_global_load_lds((const __attribute__((address_space(1))) void*)src,
                                       (__attribute__((address_space(3))) void*)(base + o), 16, 0,
                                       0);
    }
  }
}

#define PH2(BUF, MH, NH, LA, LB, WAITC)                                                           \
  {                                                                                               \
    if (LA) {                                                                                     \
      _Pragma("unroll") for (int mi = 0; mi < 2; ++mi) {                                          \
        _Pragma("unroll") for (int c = 0; c < 2; ++c) {                                           \
          af[mi][c] = *(const v8s*)(sL + (BUF)*49152 + (MH)*8192 + (mi * 16 + lr) * 256 +         \
                                    ((wm * 128 + c * 64 + lh * 16) ^ (lr << 4)));                 \
        }                                                                                         \
      }                                                                                           \
    }                                                                                             \
    if (LB) {                                                                                     \
      _Pragma("unroll") for (int ni = 0; ni < 2; ++ni) {                                          \
        _Pragma("unroll") for (int c = 0; c < 2; ++c) {                                           \
          bf[ni][c] = *(const v8s*)(sL + (BUF)*49152 + 16384 + (NH)*16384 +                       \
                                    ((wn & 1) * 32 + ni * 16 + lr) * 256 +                        \
                                    (((wn >> 1) * 128 + c * 64 + lh * 16) ^ (lr << 4)));          \
        }                                                                                         \
      }                                                                                           \
    }                                                                                             \
    stage8b(sL, Ag, Bg, row0, col0, K, n, NT2, tid);                                              \
    ++n;                                                                                          \
    if (WAITC) {                                                                                  \
      if (((n - 1) >> 2) < NT2) asm volatile("s_waitcnt vmcnt(3)" ::: "memory");                  \
      else asm volatile("s_waitcnt vmcnt(0)" ::: "memory");                                       \
    }                                                                                             \
    __builtin_amdgcn_sched_barrier(0);                                                            \
    __builtin_amdgcn_s_barrier();                                                                 \
    asm volatile("s_waitcnt lgkmcnt(0)" ::: "memory");                                            \
    __builtin_amdgcn_sched_barrier(0);                                                            \
    __builtin_amdgcn_s_setprio(1);                                                                \
    _Pragma("unroll") for (int mi = 0; mi < 2; ++mi) {                                            \
      _Pragma("unroll") for (int ni = 0; ni < 2; ++ni) {                                          \
        _Pragma("unroll") for (int c = 0; c < 2; ++c) {                                           \
          acc[(MH)*2 + mi][(NH)*2 + ni] = __builtin_amdgcn_mfma_f32_16x16x32_bf16(                \
              af[mi][c], bf[ni][c], acc[(MH)*2 + mi][(NH)*2 + ni], 0, 0, 0);                      \
        }                                                                                         \
      }                                                                                           \
    }                                                                                             \
    __builtin_amdgcn_s_setprio(0);                                                                \
    __builtin_amdgcn_sched_barrier(0);                                                            \
    __builtin_amdgcn_s_barrier();                                                                 \
  }

__global__ __launch_bounds__(512, 2) void k_gemm_bt8(const u16* __restrict__ Ag,
                                                     const u16* __restrict__ Bg,
                                                     float* __restrict__ C, int M, int N, int K) {
  __shared__ char sL[98304];
  const int tid = threadIdx.x;
  const int wid = tid >> 6, l = tid & 63;
  const int lr = l & 15, lh = l >> 4;
  const int wm = wid >> 2, wn = wid & 3;
  const int nwg = gridDim.x * gridDim.y;
  const int bid = blockIdx.y * gridDim.x + blockIdx.x;
  const int cpx = nwg >> 3;
  const int swz = (bid & 7) * cpx + (bid >> 3);
  const int row0 = (swz / gridDim.x) * 128, col0 = (swz % gridDim.x) * 256;
  const int NT2 = K >> 6;

  v4f zz = {0.f, 0.f, 0.f, 0.f};
  v4f acc[4][4];
#pragma unroll
  for (int i = 0; i < 4; ++i)
#pragma unroll
    for (int j = 0; j < 4; ++j) acc[i][j] = zz;
  v8s af[2][2], bf[2][2];

  for (int i = 0; i < 6; ++i) stage8b(sL, Ag, Bg, row0, col0, K, i, NT2, tid);
  asm volatile("s_waitcnt vmcnt(3)" ::: "memory");
  __builtin_amdgcn_sched_barrier(0);
  __builtin_amdgcn_s_barrier();

  int n = 6;
  for (int it = 0; it < NT2 / 2; ++it) {
    PH2(0, 0, 0, 1, 1, 0)
    PH2(0, 0, 1, 0, 1, 0)
    PH2(0, 1, 1, 1, 0, 0)
    PH2(0, 1, 0, 0, 1, 1)
    PH2(1, 0, 0, 1, 1, 0)
    PH2(1, 0, 1, 0, 1, 0)
    PH2(1, 1, 1, 1, 0, 0)
    PH2(1, 1, 0, 0, 1, 1)
  }

#pragma unroll
  for (int MH = 0; MH < 2; ++MH) {
#pragma unroll
    for (int mi = 0; mi < 2; ++mi) {
#pragma unroll
      for (int NH = 0; NH < 2; ++NH) {
#pragma unroll
        for (int ni = 0; ni < 2; ++ni) {
          int row = row0 + MH * 64 + wm * 32 + mi * 16 + lh * 4;
          int col = col0 + NH * 128 + (wn & 1) * 32 + (wn >> 1) * 64 + ni * 16 + lr;
          v4f a_ = acc[MH * 2 + mi][NH * 2 + ni];
#pragma unroll
          for (int r = 0; r < 4; ++r) C[(size_t)(row + r) * N + col] = a_[r];
        }
      }
    }
  }
}

// ------- causal GQA flash attention v14: R13-exact (stage AFTER QK^T) -------
// KVBLK=64, K+V double-buffered in LDS (72KB, 2 blocks/CU), paired schedule.
__global__ __launch_bounds__(256) void k_flash_attn(const u16* __restrict__ Q,
                                                    const u16* __restrict__ Kb,
                                                    const u16* __restrict__ Vt,
                                                    u16* __restrict__ O, int S, int H, int KH,
                                                    int Mtot) {
  const int bh = blockIdx.x;
  const int h = bh % H, b = bh / H;
  const int kvh = h / (H / KH);
  const int w = threadIdx.x >> 6, l = threadIdx.x & 63;
  const int lr = l & 15, lh = l >> 4;

  __shared__ alignas(16) char sK[2][16384];
  __shared__ alignas(16) char sV[2][16384];
  __shared__ alignas(16) unsigned P_lds[4][16 * 32];
  unsigned* prow = P_lds[w] + lr * 32;
  const int xr = (lr & 7) << 2;

  v4f zz = {0.f, 0.f, 0.f, 0.f};
  const int strideK = KH * 128;
  const int strideKB = strideK * 2;
  const char* KheadB = (const char*)Kb + 2 * ((size_t)b * S * strideK + (size_t)kvh * 128);
  const char* VheadB = (const char*)Vt + 2 * ((size_t)(kvh * 128) * Mtot + (size_t)b * S);
  const size_t MtotB = (size_t)Mtot * 2;

  auto stage = [&](int kv0, int bufi) {
    const char* Kt = KheadB + (size_t)kv0 * strideKB;
#pragma unroll
    for (int j = 0; j < 4; ++j) {
      int jj = w * 4 + j;
      int ci = jj * 64 + l;
      int r = ci >> 4;
      int bc = (ci & 15) << 4;
      const char* src = Kt + (size_t)r * strideKB + (bc ^ ((r & 15) << 4));
      __builtin_amdgcn_global_load_lds((const __attribute__((address_space(1))) void*)src,
                                       (__attribute__((address_space(3))) void*)(sK[bufi] + jj * 1024),
                                       16, 0, 0);
    }
    const char* Vt0 = VheadB + (size_t)kv0 * 2;
#pragma unroll
    for (int j = 0; j < 4; ++j) {
      int jj = w * 4 + j;
      int ci = jj * 64 + l;
      int r = ci >> 3;
      int bc = (ci & 7) << 4;
      const char* src = Vt0 + (size_t)r * MtotB + (bc ^ ((r & 7) << 4));
      __builtin_amdgcn_global_load_lds((const __attribute__((address_space(1))) void*)src,
                                       (__attribute__((address_space(3))) void*)(sV[bufi] + jj * 1024),
                                       16, 0, 0);
    }
  };

  for (int pp = 0; pp < 2; ++pp) {
    const int qt = (pp == 0) ? (int)blockIdx.y : (S / 64 - 1 - (int)blockIdx.y);
    const int q0 = qt * 64;
    const int nt = qt + 1;
    const int qi = q0 + w * 16 + lr;

    v8s qf[4];
    const u16* qp = Q + (size_t)(b * S + q0 + w * 16 + lr) * (size_t)(H * 128) + h * 128 + lh * 8;
#pragma unroll
    for (int c = 0; c < 4; ++c) qf[c] = *(const v8s*)(qp + c * 32);

    v4f o_acc[8];
#pragma unroll
    for (int df = 0; df < 8; ++df) o_acc[df] = zz;
    float m_run = -1e30f, l_run = 0.f;

    stage(0, 0);
    __syncthreads();

    int buf = 0;
    for (int t = 0; t < nt; ++t) {
      const int kv0 = t * 64;
      const bool lastTile = (t == nt - 1);
      const char* sKb = sK[buf];
      const char* sVb = sV[buf];

      // ---- QK^T swapped (C rows=kv, cols=q), K from LDS ----
      v4f sv[4];
      __builtin_amdgcn_s_setprio(1);
#pragma unroll
      for (int nf = 0; nf < 4; ++nf) {
        v4f a_ = zz;
        const int r = nf * 16 + lr;
#pragma unroll
        for (int c = 0; c < 4; ++c) {
          v8s kf = *(const v8s*)(sKb + r * 256 + ((lh * 16 + c * 64) ^ (lr << 4)));
          a_ = __builtin_amdgcn_mfma_f32_16x16x32_bf16(kf, qf[c], a_, 0, 0, 0);
        }
        sv[nf] = a_;
      }
      __builtin_amdgcn_s_setprio(0);

      // ---- stage next tile (R13 placement: after QK^T) ----
      if (t + 1 < nt) stage(kv0 + 64, buf ^ 1);

      if (lastTile) {
#pragma unroll
        for (int nf = 0; nf < 4; ++nf)
#pragma unroll
          for (int r = 0; r < 4; ++r)
            if (kv0 + nf * 16 + lh * 4 + r > qi) sv[nf][r] = -1e30f;
      }
      float pm0 = fmaxf(fmaxf(sv[0][0], sv[0][1]), fmaxf(sv[0][2], sv[0][3]));
      float pm1 = fmaxf(fmaxf(sv[1][0], sv[1][1]), fmaxf(sv[1][2], sv[1][3]));
      float pm2 = fmaxf(fmaxf(sv[2][0], sv[2][1]), fmaxf(sv[2][2], sv[2][3]));
      float pm3 = fmaxf(fmaxf(sv[3][0], sv[3][1]), fmaxf(sv[3][2], sv[3][3]));
      float pmax = fmaxf(fmaxf(pm0, pm1), fmaxf(pm2, pm3));
      pmax = fmaxf(pmax, __shfl_xor(pmax, 16, 64));
      pmax = fmaxf(pmax, __shfl_xor(pmax, 32, 64));
      if (!__all(pmax - m_run <= 8.0f)) {  // T13 defer-max
        float mnew = fmaxf(m_run, pmax);
        float corr = exp2f(m_run - mnew);
        l_run *= corr;
        m_run = mnew;
        float corrq[4];
#pragma unroll
        for (int r = 0; r < 4; ++r) corrq[r] = __shfl(corr, lh * 4 + r, 16);
#pragma unroll
        for (int df = 0; df < 8; ++df)
#pragma unroll
          for (int r = 0; r < 4; ++r) o_acc[df][r] *= corrq[r];
      }
      float rsum = 0.f;
#pragma unroll
      for (int nf = 0; nf < 4; ++nf)
#pragma unroll
        for (int r = 0; r < 4; ++r) {
          float pv = exp2f(sv[nf][r] - m_run);
          sv[nf][r] = pv;
          rsum += pv;
        }
      rsum += __shfl_xor(rsum, 16, 64);
      rsum += __shfl_xor(rsum, 32, 64);
      l_run += rsum;

#pragma unroll
      for (int nf = 0; nf < 4; ++nf) {
        v2u pw;
        pw[0] = pk2(sv[nf][0], sv[nf][1]);
        pw[1] = pk2(sv[nf][2], sv[nf][3]);
        *(v2u*)(prow + ((nf * 8 + lh * 2) ^ xr)) = pw;
      }
      asm volatile("s_waitcnt lgkmcnt(0)" ::: "memory");
      __builtin_amdgcn_sched_barrier(0);  // rule 18
      v8s ap[2];
#pragma unroll
      for (int c2 = 0; c2 < 2; ++c2) ap[c2] = *(const v8s*)(prow + ((c2 * 16 + lh * 4) ^ xr));

      __builtin_amdgcn_s_setprio(1);
#pragma unroll
      for (int df = 0; df < 8; ++df) {
        const int r = df * 16 + lr;
        const char* vrow = sVb + r * 128;
        const int key = (lr & 7) << 4;
#pragma unroll
        for (int c2 = 0; c2 < 2; ++c2) {
          v8s vf = *(const v8s*)(vrow + ((lh * 16 + c2 * 64) ^ key));
          o_acc[df] = __builtin_amdgcn_mfma_f32_16x16x32_bf16(ap[c2], vf, o_acc[df], 0, 0, 0);
        }
      }
      __builtin_amdgcn_s_setprio(0);

      __syncthreads();
      buf ^= 1;
    }

    float rl = 1.0f / l_run;
    float invq[4];
#pragma unroll
    for (int r = 0; r < 4; ++r) invq[r] = __shfl(rl, lh * 4 + r, 16);
    u16* op = O + (size_t)(b * S + q0 + w * 16 + lh * 4) * (size_t)(H * 128) + h * 128;
#pragma unroll
    for (int r = 0; r < 4; ++r)
#pragma unroll
      for (int df = 0; df < 8; ++df)
        op[(size_t)r * (H * 128) + df * 16 + lr] = f2bf(o_acc[df][r] * invq[r]);
  }
}

extern "C" void kernel_launch(void* const* d_in, const int* in_sizes, int n_in, void* d_out,
                              int out_size, void* d_ws, size_t ws_size, hipStream_t stream) {
  const float* x = (const float*)d_in[0];
  const float* Wq = (const float*)d_in[1];
  const float* Wk = (const float*)d_in[2];
  const float* Wv = (const float*)d_in[3];
  const float* Wp = (const float*)d_in[4];
  const float* gain = (const float*)d_in[5];
  float* out = (float*)d_out;

  const int B = 2, S = 2048, D = 2048, H = 16, KH = 4;
  const int M = B * S;
  const int KVD = KH * 128;
  const int NQKV = D + 2 * KVD;  // 3072

  char* w = (char*)d_ws;
  u16* x_bf = (u16*)w;   w += (size_t)M * D * 2;
  u16* wqkv = (u16*)w;   w += (size_t)NQKV * D * 2;
  u16* wp_bf = (u16*)w;  w += (size_t)D * D * 2;
  u16* q_bf = (u16*)w;   w += (size_t)M * D * 2;
  u16* k_bf = (u16*)w;   w += (size_t)M * KVD * 2;
  u16* v_t = (u16*)w;    w += (size_t)M * KVD * 2;
  u16* ao_bf = (u16*)w;  w += (size_t)M * D * 2;
  float* cosT = (float*)w; w += (size_t)S * 64 * 4;
  float* sinT = (float*)w; w += (size_t)S * 64 * 4;
  if ((size_t)(w - (char*)d_ws) > ws_size) return;

  k_cast_bf16<<<(M * D / 4 + 255) / 256, 256, 0, stream>>>(x, x_bf, M * D / 4);
  {
    int na4 = D * D / 4, nb4 = KVD * D / 4, nc4 = KVD * D / 4, nd4 = D * D / 4;
    int tot = na4 + nb4 + nc4 + nd4;
    k_cast_w<<<(tot + 255) / 256, 256, 0, stream>>>(
        Wq, Wk, Wv, Wp, wqkv, wqkv + (size_t)D * D, wqkv + (size_t)(D + KVD) * D, wp_bf,
        na4, nb4, nc4, nd4);
  }

  double scale = (double)S / 1024.0;
  double base = (S > 1024) ? 10000.0 * pow(scale, 128.0 / 126.0) : 10000.0;
  float l2b = (float)(log(base) / log(2.0));
  k_rope_tab<<<S * 64 / 256, 256, 0, stream>>>(cosT, sinT, l2b);

  dim3 gqkv(NQKV / 384, M / 128);  // 8 x 32 = 256 blocks = 1/CU
  k_gemm_qkv8<<<gqkv, 512, 0, stream>>>(x_bf, wqkv, q_bf, k_bf, v_t, M, D);

  float qscale = 1.4426950408889634f / sqrtf(128.0f);
  {
    int MH_ = M * H, MKH_ = M * KH;
    int rows = MH_ + MKH_;
    k_rmsnorm_rope2<<<rows / 4, 256, 0, stream>>>(q_bf, k_bf, cosT, sinT, gain, MH_, MKH_, S,
                                                  qscale);
  }

  dim3 blk(256);
  dim3 ga(B * H, S / 128);  // 512 blocks, paired q-tiles {y, 31-y}
  k_flash_attn<<<ga, blk, 0, stream>>>(q_bf, k_bf, v_t, ao_bf, S, H, KH, M);

  dim3 gp(D / 256, M / 128);  // 8 x 32 = 256 blocks = 1/CU
  k_gemm_bt8<<<gp, 512, 0, stream>>>(ao_bf, wp_bf, out, M, D, D);
}

// Round 17
// 201.940 us; speedup vs baseline: 1.1517x; 1.0116x over previous
//
#include <hip/hip_runtime.h>
#include <cmath>

typedef unsigned short u16;
typedef short v8s __attribute__((ext_vector_type(8)));
typedef float v4f __attribute__((ext_vector_type(4)));
typedef unsigned short v4u __attribute__((ext_vector_type(4)));
typedef unsigned int v2u __attribute__((ext_vector_type(2)));

__device__ __forceinline__ u16 f2bf(float f) {
  unsigned u = __builtin_bit_cast(unsigned, f);
  u += 0x7fffu + ((u >> 16) & 1u);
  return (u16)(u >> 16);
}
__device__ __forceinline__ float bf2f(u16 h) {
  unsigned u = ((unsigned)h) << 16;
  return __builtin_bit_cast(float, u);
}
// T12: hardware packed f32->bf16x2
__device__ __forceinline__ unsigned pk2(float a, float b) {
  unsigned r;
  asm("v_cvt_pk_bf16_f32 %0, %1, %2" : "=v"(r) : "v"(a), "v"(b));
  return r;
}

// ---- merged preprocessing: RoPE table + all fp32->bf16 casts (one launch) ----
__global__ void k_prep(const float* __restrict__ x, const float* __restrict__ Wq,
                       const float* __restrict__ Wk, const float* __restrict__ Wv,
                       const float* __restrict__ Wp, u16* __restrict__ x_bf,
                       u16* __restrict__ wqkv, u16* __restrict__ wp_bf,
                       float* __restrict__ cosT, float* __restrict__ sinT, float l2b,
                       int nr, int nx4, int nq4, int nk4, int nv4, int np4) {
  int idx = blockIdx.x * blockDim.x + threadIdx.x;
  if (idx < nr) {  // RoPE table element
    int t = idx >> 6, i = idx & 63;
    float inv = exp2f(-(float)i * (1.0f / 64.0f) * l2b);
    float fr = (float)t * inv;
    cosT[idx] = cosf(fr);
    sinT[idx] = sinf(fr);
    return;
  }
  int j = idx - nr;  // quad index over [x | Wq | Wk | Wv | Wp]
  const float* src;
  u16* dst;
  if (j < nx4) { src = x; dst = x_bf; }
  else {
    j -= nx4;
    if (j < nq4) { src = Wq; dst = wqkv; }
    else {
      j -= nq4;
      if (j < nk4) { src = Wk; dst = wqkv + (size_t)2048 * 2048; }
      else {
        j -= nk4;
        if (j < nv4) { src = Wv; dst = wqkv + (size_t)2560 * 2048; }
        else {
          j -= nv4;
          if (j >= np4) return;
          src = Wp; dst = wp_bf;
        }
      }
    }
  }
  v4f v = ((const v4f*)src)[j];
  v4u o;
  o[0] = f2bf(v[0]); o[1] = f2bf(v[1]); o[2] = f2bf(v[2]); o[3] = f2bf(v[3]);
  ((v4u*)dst)[j] = o;
}

// ---- fused per-head RMSNorm + RoPE + gain for BOTH q and k (one launch) ----
__global__ void k_rmsnorm_rope2(u16* __restrict__ qb, u16* __restrict__ kb,
                                const float* __restrict__ cosT, const float* __restrict__ sinT,
                                const float* __restrict__ gain, int MH, int MKH, int S,
                                float qscale) {
  int idx = blockIdx.x * 4 + (threadIdx.x >> 6);
  int l = threadIdx.x & 63;
  u16* p;
  float g;
  int s;
  if (idx < MH) {
    p = qb + (size_t)idx * 128;
    g = qscale * gain[idx & 15];
    s = (idx >> 4) & (S - 1);
  } else {
    int j = idx - MH;
    if (j >= MKH) return;
    p = kb + (size_t)j * 128;
    g = 1.0f;
    s = (j >> 2) & (S - 1);
  }
  float a = bf2f(p[l]), b = bf2f(p[64 + l]);
  float ss = a * a + b * b;
#pragma unroll
  for (int o = 32; o; o >>= 1) ss += __shfl_xor(ss, o, 64);
  float r = rsqrtf(ss * (1.0f / 128.0f) + 1.1920929e-7f);
  a *= r; b *= r;
  float c = cosT[s * 64 + l], sn = sinT[s * 64 + l];
  p[l] = f2bf((a * c + b * sn) * g);
  p[64 + l] = f2bf((b * c - a * sn) * g);
}

// ======== 128x384 8-phase QKV GEMM (T1+T2+T3+T4+T5), BK=64, 512 thr =========
__device__ __forceinline__ void stage8(char* sL, const u16* __restrict__ Ag,
                                       const u16* __restrict__ Bg, int row0, int col0, int K,
                                       int n, int NT2, int tid) {
  int tile = n >> 2;
  if (tile >= NT2) return;
  int part = n & 3;  // 0:A-h0 1:B-h1 2:A-h1 3:B-h0
  int isB = part & 1;
  int half = (part == 1 || part == 2) ? 1 : 0;
  int k0 = tile * 64;
  if (!isB) {
    char* base = sL + (tile & 1) * 65536 + half * 8192;
    int o = tid * 16;
    int rowp = o >> 8;
    int un = (o & 255) ^ ((rowp & 15) << 4);
    int rsub = rowp + ((un >> 7) << 5);
    int k = (un & 127) >> 1;
    const u16* src = Ag + (size_t)(row0 + half * 64 + rsub) * K + (k0 + k);
    __builtin_amdgcn_global_load_lds((const __attribute__((address_space(1))) void*)src,
                                     (__attribute__((address_space(3))) void*)(base + o), 16, 0, 0);
  } else {
    char* base = sL + (tile & 1) * 65536 + 16384 + half * 24576;
#pragma unroll
    for (int j = 0; j < 3; ++j) {
      int o = (j * 512 + tid) * 16;
      int rowp = o >> 8;
      int un = (o & 255) ^ ((rowp & 15) << 4);
      int rsub = rowp + (un >> 7) * 96;
      int k = (un & 127) >> 1;
      const u16* src = Bg + (size_t)(col0 + half * 192 + rsub) * K + (k0 + k);
      __builtin_amdgcn_global_load_lds((const __attribute__((address_space(1))) void*)src,
                                       (__attribute__((address_space(3))) void*)(base + o), 16, 0,
                                       0);
    }
  }
}

#define PH(BUF, MH, NH, LA, LB, WAITC)                                                            \
  {                                                                                               \
    if (LA) {                                                                                     \
      _Pragma("unroll") for (int mi = 0; mi < 2; ++mi) {                                          \
        _Pragma("unroll") for (int c = 0; c < 2; ++c) {                                           \
          af[mi][c] = *(const v8s*)(sL + (BUF)*65536 + (MH)*8192 + (mi * 16 + lr) * 256 +         \
                                    ((wm * 128 + c * 64 + lh * 16) ^ (lr << 4)));                 \
        }                                                                                         \
      }                                                                                           \
    }                                                                                             \
    if (LB) {                                                                                     \
      _Pragma("unroll") for (int ni = 0; ni < 3; ++ni) {                                          \
        _Pragma("unroll") for (int c = 0; c < 2; ++c) {                                           \
          bf[ni][c] = *(const v8s*)(sL + (BUF)*65536 + 16384 + (NH)*24576 +                       \
                                    ((wn & 1) * 48 + ni * 16 + lr) * 256 +                        \
                                    (((wn >> 1) * 128 + c * 64 + lh * 16) ^ (lr << 4)));          \
        }                                                                                         \
      }                                                                                           \
    }                                                                                             \
    stage8(sL, Ag, Bg, row0, col0, K, n, NT2, tid);                                               \
    ++n;                                                                                         \
    if (WAITC) {                                                                                  \
      if (((n - 1) >> 2) < NT2) asm volatile("s_waitcnt vmcnt(4)" ::: "memory");                  \
      else asm volatile("s_waitcnt vmcnt(0)" ::: "memory");                                       \
    }                                                                                             \
    __builtin_amdgcn_sched_barrier(0);                                                            \
    __builtin_amdgcn_s_barrier();                                                                 \
    asm volatile("s_waitcnt lgkmcnt(0)" ::: "memory");                                            \
    __builtin_amdgcn_sched_barrier(0);                                                            \
    __builtin_amdgcn_s_setprio(1);                                                                \
    _Pragma("unroll") for (int mi = 0; mi < 2; ++mi) {                                            \
      _Pragma("unroll") for (int ni = 0; ni < 3; ++ni) {                                          \
        _Pragma("unroll") for (int c = 0; c < 2; ++c) {                                           \
          acc[(MH)*2 + mi][(NH)*3 + ni] = __builtin_amdgcn_mfma_f32_16x16x32_bf16(                \
              af[mi][c], bf[ni][c], acc[(MH)*2 + mi][(NH)*3 + ni], 0, 0, 0);                      \
        }                                                                                         \
      }                                                                                           \
    }                                                                                             \
    __builtin_amdgcn_s_setprio(0);                                                                \
    __builtin_amdgcn_sched_barrier(0);                                                            \
    __builtin_amdgcn_s_barrier();                                                                 \
  }

__global__ __launch_bounds__(512, 2) void k_gemm_qkv8(const u16* __restrict__ Ag,
                                                      const u16* __restrict__ Bg,
                                                      u16* __restrict__ q_o, u16* __restrict__ k_o,
                                                      u16* __restrict__ v_o, int M, int K) {
  __shared__ char sL[131072];
  const int tid = threadIdx.x;
  const int wid = tid >> 6, l = tid & 63;
  const int lr = l & 15, lh = l >> 4;
  const int wm = wid >> 2, wn = wid & 3;
  const int nwg = gridDim.x * gridDim.y;
  const int bid = blockIdx.y * gridDim.x + blockIdx.x;
  const int cpx = nwg >> 3;
  const int swz = (bid & 7) * cpx + (bid >> 3);
  const int row0 = (swz / gridDim.x) * 128, col0 = (swz % gridDim.x) * 384;
  const int NT2 = K >> 6;

  v4f zz = {0.f, 0.f, 0.f, 0.f};
  v4f acc[4][6];
#pragma unroll
  for (int i = 0; i < 4; ++i)
#pragma unroll
    for (int j = 0; j < 6; ++j) acc[i][j] = zz;
  v8s af[2][2], bf[3][2];

  for (int i = 0; i < 6; ++i) stage8(sL, Ag, Bg, row0, col0, K, i, NT2, tid);
  asm volatile("s_waitcnt vmcnt(4)" ::: "memory");
  __builtin_amdgcn_sched_barrier(0);
  __builtin_amdgcn_s_barrier();

  int n = 6;
  for (int it = 0; it < NT2 / 2; ++it) {
    PH(0, 0, 0, 1, 1, 0)
    PH(0, 0, 1, 0, 1, 0)
    PH(0, 1, 1, 1, 0, 0)
    PH(0, 1, 0, 0, 1, 1)
    PH(1, 0, 0, 1, 1, 0)
    PH(1, 0, 1, 0, 1, 0)
    PH(1, 1, 1, 1, 0, 0)
    PH(1, 1, 0, 0, 1, 1)
  }

#pragma unroll
  for (int MH = 0; MH < 2; ++MH) {
#pragma unroll
    for (int mi = 0; mi < 2; ++mi) {
#pragma unroll
      for (int NH = 0; NH < 2; ++NH) {
#pragma unroll
        for (int ni = 0; ni < 3; ++ni) {
          int row = row0 + MH * 64 + wm * 32 + mi * 16 + lh * 4;
          int col = col0 + NH * 192 + wn * 48 + ni * 16 + lr;
          v4f a_ = acc[MH * 2 + mi][NH * 3 + ni];
          if (col < 2048) {
#pragma unroll
            for (int r = 0; r < 4; ++r) q_o[(size_t)(row + r) * 2048 + col] = f2bf(a_[r]);
          } else if (col < 2560) {
#pragma unroll
            for (int r = 0; r < 4; ++r) k_o[(size_t)(row + r) * 512 + (col - 2048)] = f2bf(a_[r]);
          } else {
#pragma unroll
            for (int r = 0; r < 4; ++r) v_o[(size_t)(col - 2560) * M + row + r] = f2bf(a_[r]);
          }
        }
      }
    }
  }
}

// ======== 128x256 8-phase out-proj GEMM (f32 C), BK=64, 512 thr =========
__device__ __forceinline__ void stage8b(char* sL, const u16* __restrict__ Ag,
                                        const u16* __restrict__ Bg, int row0, int col0, int K,
                                        int n, int NT2, int tid) {
  int tile = n >> 2;
  if (tile >= NT2) return;
  int part = n & 3;
  int isB = part & 1;
  int half = (part == 1 || part == 2) ? 1 : 0;
  int k0 = tile * 64;
  if (!isB) {
    char* base = sL + (tile & 1) * 49152 + half * 8192;
    int o = tid * 16;
    int rowp = o >> 8;
    int un = (o & 255) ^ ((rowp & 15) << 4);
    int rsub = rowp + ((un >> 7) << 5);
    int k = (un & 127) >> 1;
    const u16* src = Ag + (size_t)(row0 + half * 64 + rsub) * K + (k0 + k);
    __builtin_amdgcn_global_load_lds((const __attribute__((address_space(1))) void*)src,
                                     (__attribute__((address_space(3))) void*)(base + o), 16, 0, 0);
  } else {
    char* base = sL + (tile & 1) * 49152 + 16384 + half * 16384;
#pragma unroll
    for (int j = 0; j < 2; ++j) {
      int o = (j * 512 + tid) * 16;
      int rowp = o >> 8;
      int un = (o & 255) ^ ((rowp & 15) << 4);
      int rsub = rowp + (un >> 7) * 64;
      int k = (un & 127) >> 1;
      const u16* src = Bg + (size_t)(col0 + half * 128 + rsub) * K + (k0 + k);
      __builtin_amdgcn_global_load_lds((const __attribute__((address_space(1))) void*)src,
                                       (__attribute__((address_space(3))) void*)(base + o), 16, 0,
                                       0);
    }
  }
}

#define PH2(BUF, MH, NH, LA, LB, WAITC)                                                           \
  {                                                                                               \
    if (LA) {                                                                                     \
      _Pragma("unroll") for (int mi = 0; mi < 2; ++mi) {                                          \
        _Pragma("unroll") for (int c = 0; c < 2; ++c) {                                           \
          af[mi][c] = *(const v8s*)(sL + (BUF)*49152 + (MH)*8192 + (mi * 16 + lr) * 256 +         \
                                    ((wm * 128 + c * 64 + lh * 16) ^ (lr << 4)));                 \
        }                                                                                         \
      }                                                                                           \
    }                                                                                             \
    if (LB) {                                                                                     \
      _Pragma("unroll") for (int ni = 0; ni < 2; ++ni) {                                          \
        _Pragma("unroll") for (int c = 0; c < 2; ++c) {                                           \
          bf[ni][c] = *(const v8s*)(sL + (BUF)*49152 + 16384 + (NH)*16384 +                       \
                                    ((wn & 1) * 32 + ni * 16 + lr) * 256 +                        \
                                    (((wn >> 1) * 128 + c * 64 + lh * 16) ^ (lr << 4)));          \
        }                                                                                         \
      }                                                                                           \
    }                                                                                             \
    stage8b(sL, Ag, Bg, row0, col0, K, n, NT2, tid);                                              \
    ++n;                                                                                         \
    if (WAITC) {                                                                                  \
      if (((n - 1) >> 2) < NT2) asm volatile("s_waitcnt vmcnt(3)" ::: "memory");                  \
      else asm volatile("s_waitcnt vmcnt(0)" ::: "memory");                                       \
    }                                                                                             \
    __builtin_amdgcn_sched_barrier(0);                                                            \
    __builtin_amdgcn_s_barrier();                                                                 \
    asm volatile("s_waitcnt lgkmcnt(0)" ::: "memory");                                            \
    __builtin_amdgcn_sched_barrier(0);                                                            \
    __builtin_amdgcn_s_setprio(1);                                                                \
    _Pragma("unroll") for (int mi = 0; mi < 2; ++mi) {                                            \
      _Pragma("unroll") for (int ni = 0; ni < 2; ++ni) {                                          \
        _Pragma("unroll") for (int c = 0; c < 2; ++c) {                                           \
          acc[(MH)*2 + mi][(NH)*2 + ni] = __builtin_amdgcn_mfma_f32_16x16x32_bf16(                \
              af[mi][c], bf[ni][c], acc[(MH)*2 + mi][(NH)*2 + ni], 0, 0, 0);                      \
        }                                                                                         \
      }                                                                                           \
    }                                                                                             \
    __builtin_amdgcn_s_setprio(0);                                                                \
    __builtin_amdgcn_sched_barrier(0);                                                            \
    __builtin_amdgcn_s_barrier();                                                                 \
  }

__global__ __launch_bounds__(512, 2) void k_gemm_bt8(const u16* __restrict__ Ag,
                                                     const u16* __restrict__ Bg,
                                                     float* __restrict__ C, int M, int N, int K) {
  __shared__ char sL[98304];
  const int tid = threadIdx.x;
  const int wid = tid >> 6, l = tid & 63;
  const int lr = l & 15, lh = l >> 4;
  const int wm = wid >> 2, wn = wid & 3;
  const int nwg = gridDim.x * gridDim.y;
  const int bid = blockIdx.y * gridDim.x + blockIdx.x;
  const int cpx = nwg >> 3;
  const int swz = (bid & 7) * cpx + (bid >> 3);
  const int row0 = (swz / gridDim.x) * 128, col0 = (swz % gridDim.x) * 256;
  const int NT2 = K >> 6;

  v4f zz = {0.f, 0.f, 0.f, 0.f};
  v4f acc[4][4];
#pragma unroll
  for (int i = 0; i < 4; ++i)
#pragma unroll
    for (int j = 0; j < 4; ++j) acc[i][j] = zz;
  v8s af[2][2], bf[2][2];

  for (int i = 0; i < 6; ++i) stage8b(sL, Ag, Bg, row0, col0, K, i, NT2, tid);
  asm volatile("s_waitcnt vmcnt(3)" ::: "memory");
  __builtin_amdgcn_sched_barrier(0);
  __builtin_amdgcn_s_barrier();

  int n = 6;
  for (int it = 0; it < NT2 / 2; ++it) {
    PH2(0, 0, 0, 1, 1, 0)
    PH2(0, 0, 1, 0, 1, 0)
    PH2(0, 1, 1, 1, 0, 0)
    PH2(0, 1, 0, 0, 1, 1)
    PH2(1, 0, 0, 1, 1, 0)
    PH2(1, 0, 1, 0, 1, 0)
    PH2(1, 1, 1, 1, 0, 0)
    PH2(1, 1, 0, 0, 1, 1)
  }

#pragma unroll
  for (int MH = 0; MH < 2; ++MH) {
#pragma unroll
    for (int mi = 0; mi < 2; ++mi) {
#pragma unroll
      for (int NH = 0; NH < 2; ++NH) {
#pragma unroll
        for (int ni = 0; ni < 2; ++ni) {
          int row = row0 + MH * 64 + wm * 32 + mi * 16 + lh * 4;
          int col = col0 + NH * 128 + (wn & 1) * 32 + (wn >> 1) * 64 + ni * 16 + lr;
          v4f a_ = acc[MH * 2 + mi][NH * 2 + ni];
#pragma unroll
          for (int r = 0; r < 4; ++r) C[(size_t)(row + r) * N + col] = a_[r];
        }
      }
    }
  }
}

// ------- causal GQA flash attention (R13/R16 structure, converged) ----------
__global__ __launch_bounds__(256) void k_flash_attn(const u16* __restrict__ Q,
                                                    const u16* __restrict__ Kb,
                                                    const u16* __restrict__ Vt,
                                                    u16* __restrict__ O, int S, int H, int KH,
                                                    int Mtot) {
  const int bh = blockIdx.x;
  const int h = bh % H, b = bh / H;
  const int kvh = h / (H / KH);
  const int w = threadIdx.x >> 6, l = threadIdx.x & 63;
  const int lr = l & 15, lh = l >> 4;

  __shared__ alignas(16) char sK[2][16384];
  __shared__ alignas(16) char sV[2][16384];
  __shared__ alignas(16) unsigned P_lds[4][16 * 32];
  unsigned* prow = P_lds[w] + lr * 32;
  const int xr = (lr & 7) << 2;

  v4f zz = {0.f, 0.f, 0.f, 0.f};
  const int strideK = KH * 128;
  const int strideKB = strideK * 2;
  const char* KheadB = (const char*)Kb + 2 * ((size_t)b * S * strideK + (size_t)kvh * 128);
  const char* VheadB = (const char*)Vt + 2 * ((size_t)(kvh * 128) * Mtot + (size_t)b * S);
  const size_t MtotB = (size_t)Mtot * 2;

  auto stage = [&](int kv0, int bufi) {
    const char* Kt = KheadB + (size_t)kv0 * strideKB;
#pragma unroll
    for (int j = 0; j < 4; ++j) {
      int jj = w * 4 + j;
      int ci = jj * 64 + l;
      int r = ci >> 4;
      int bc = (ci & 15) << 4;
      const char* src = Kt + (size_t)r * strideKB + (bc ^ ((r & 15) << 4));
      __builtin_amdgcn_global_load_lds((const __attribute__((address_space(1))) void*)src,
                                       (__attribute__((address_space(3))) void*)(sK[bufi] + jj * 1024),
                                       16, 0, 0);
    }
    const char* Vt0 = VheadB + (size_t)kv0 * 2;
#pragma unroll
    for (int j = 0; j < 4; ++j) {
      int jj = w * 4 + j;
      int ci = jj * 64 + l;
      int r = ci >> 3;
      int bc = (ci & 7) << 4;
      const char* src = Vt0 + (size_t)r * MtotB + (bc ^ ((r & 7) << 4));
      __builtin_amdgcn_global_load_lds((const __attribute__((address_space(1))) void*)src,
                                       (__attribute__((address_space(3))) void*)(sV[bufi] + jj * 1024),
                                       16, 0, 0);
    }
  };

  for (int pp = 0; pp < 2; ++pp) {
    const int qt = (pp == 0) ? (int)blockIdx.y : (S / 64 - 1 - (int)blockIdx.y);
    const int q0 = qt * 64;
    const int nt = qt + 1;
    const int qi = q0 + w * 16 + lr;

    v8s qf[4];
    const u16* qp = Q + (size_t)(b * S + q0 + w * 16 + lr) * (size_t)(H * 128) + h * 128 + lh * 8;
#pragma unroll
    for (int c = 0; c < 4; ++c) qf[c] = *(const v8s*)(qp + c * 32);

    v4f o_acc[8];
#pragma unroll
    for (int df = 0; df < 8; ++df) o_acc[df] = zz;
    float m_run = -1e30f, l_run = 0.f;

    stage(0, 0);
    __syncthreads();

    int buf = 0;
    for (int t = 0; t < nt; ++t) {
      const int kv0 = t * 64;
      const bool lastTile = (t == nt - 1);
      const char* sKb = sK[buf];
      const char* sVb = sV[buf];

      v4f sv[4];
      __builtin_amdgcn_s_setprio(1);
#pragma unroll
      for (int nf = 0; nf < 4; ++nf) {
        v4f a_ = zz;
        const int r = nf * 16 + lr;
#pragma unroll
        for (int c = 0; c < 4; ++c) {
          v8s kf = *(const v8s*)(sKb + r * 256 + ((lh * 16 + c * 64) ^ (lr << 4)));
          a_ = __builtin_amdgcn_mfma_f32_16x16x32_bf16(kf, qf[c], a_, 0, 0, 0);
        }
        sv[nf] = a_;
      }
      __builtin_amdgcn_s_setprio(0);

      if (t + 1 < nt) stage(kv0 + 64, buf ^ 1);

      if (lastTile) {
#pragma unroll
        for (int nf = 0; nf < 4; ++nf)
#pragma unroll
          for (int r = 0; r < 4; ++r)
            if (kv0 + nf * 16 + lh * 4 + r > qi) sv[nf][r] = -1e30f;
      }
      float pm0 = fmaxf(fmaxf(sv[0][0], sv[0][1]), fmaxf(sv[0][2], sv[0][3]));
      float pm1 = fmaxf(fmaxf(sv[1][0], sv[1][1]), fmaxf(sv[1][2], sv[1][3]));
      float pm2 = fmaxf(fmaxf(sv[2][0], sv[2][1]), fmaxf(sv[2][2], sv[2][3]));
      float pm3 = fmaxf(fmaxf(sv[3][0], sv[3][1]), fmaxf(sv[3][2], sv[3][3]));
      float pmax = fmaxf(fmaxf(pm0, pm1), fmaxf(pm2, pm3));
      pmax = fmaxf(pmax, __shfl_xor(pmax, 16, 64));
      pmax = fmaxf(pmax, __shfl_xor(pmax, 32, 64));
      if (!__all(pmax - m_run <= 8.0f)) {  // T13 defer-max
        float mnew = fmaxf(m_run, pmax);
        float corr = exp2f(m_run - mnew);
        l_run *= corr;
        m_run = mnew;
        float corrq[4];
#pragma unroll
        for (int r = 0; r < 4; ++r) corrq[r] = __shfl(corr, lh * 4 + r, 16);
#pragma unroll
        for (int df = 0; df < 8; ++df)
#pragma unroll
          for (int r = 0; r < 4; ++r) o_acc[df][r] *= corrq[r];
      }
      float rsum = 0.f;
#pragma unroll
      for (int nf = 0; nf < 4; ++nf)
#pragma unroll
        for (int r = 0; r < 4; ++r) {
          float pv = exp2f(sv[nf][r] - m_run);
          sv[nf][r] = pv;
          rsum += pv;
        }
      rsum += __shfl_xor(rsum, 16, 64);
      rsum += __shfl_xor(rsum, 32, 64);
      l_run += rsum;

#pragma unroll
      for (int nf = 0; nf < 4; ++nf) {
        v2u pw;
        pw[0] = pk2(sv[nf][0], sv[nf][1]);
        pw[1] = pk2(sv[nf][2], sv[nf][3]);
        *(v2u*)(prow + ((nf * 8 + lh * 2) ^ xr)) = pw;
      }
      asm volatile("s_waitcnt lgkmcnt(0)" ::: "memory");
      __builtin_amdgcn_sched_barrier(0);  // rule 18
      v8s ap[2];
#pragma unroll
      for (int c2 = 0; c2 < 2; ++c2) ap[c2] = *(const v8s*)(prow + ((c2 * 16 + lh * 4) ^ xr));

      __builtin_amdgcn_s_setprio(1);
#pragma unroll
      for (int df = 0; df < 8; ++df) {
        const int r = df * 16 + lr;
        const char* vrow = sVb + r * 128;
        const int key = (lr & 7) << 4;
#pragma unroll
        for (int c2 = 0; c2 < 2; ++c2) {
          v8s vf = *(const v8s*)(vrow + ((lh * 16 + c2 * 64) ^ key));
          o_acc[df] = __builtin_amdgcn_mfma_f32_16x16x32_bf16(ap[c2], vf, o_acc[df], 0, 0, 0);
        }
      }
      __builtin_amdgcn_s_setprio(0);

      __syncthreads();
      buf ^= 1;
    }

    float rl = 1.0f / l_run;
    float invq[4];
#pragma unroll
    for (int r = 0; r < 4; ++r) invq[r] = __shfl(rl, lh * 4 + r, 16);
    u16* op = O + (size_t)(b * S + q0 + w * 16 + lh * 4) * (size_t)(H * 128) + h * 128;
#pragma unroll
    for (int r = 0; r < 4; ++r)
#pragma unroll
      for (int df = 0; df < 8; ++df)
        op[(size_t)r * (H * 128) + df * 16 + lr] = f2bf(o_acc[df][r] * invq[r]);
  }
}

extern "C" void kernel_launch(void* const* d_in, const int* in_sizes, int n_in, void* d_out,
                              int out_size, void* d_ws, size_t ws_size, hipStream_t stream) {
  const float* x = (const float*)d_in[0];
  const float* Wq = (const float*)d_in[1];
  const float* Wk = (const float*)d_in[2];
  const float* Wv = (const float*)d_in[3];
  const float* Wp = (const float*)d_in[4];
  const float* gain = (const float*)d_in[5];
  float* out = (float*)d_out;

  const int B = 2, S = 2048, D = 2048, H = 16, KH = 4;
  const int M = B * S;
  const int KVD = KH * 128;
  const int NQKV = D + 2 * KVD;  // 3072

  char* w = (char*)d_ws;
  u16* x_bf = (u16*)w;   w += (size_t)M * D * 2;
  u16* wqkv = (u16*)w;   w += (size_t)NQKV * D * 2;
  u16* wp_bf = (u16*)w;  w += (size_t)D * D * 2;
  u16* q_bf = (u16*)w;   w += (size_t)M * D * 2;
  u16* k_bf = (u16*)w;   w += (size_t)M * KVD * 2;
  u16* v_t = (u16*)w;    w += (size_t)M * KVD * 2;
  u16* ao_bf = (u16*)w;  w += (size_t)M * D * 2;
  float* cosT = (float*)w; w += (size_t)S * 64 * 4;
  float* sinT = (float*)w; w += (size_t)S * 64 * 4;
  if ((size_t)(w - (char*)d_ws) > ws_size) return;

  double scale = (double)S / 1024.0;
  double base = (S > 1024) ? 10000.0 * pow(scale, 128.0 / 126.0) : 10000.0;
  float l2b = (float)(log(base) / log(2.0));

  {
    int nr = S * 64;
    int nx4 = M * D / 4;
    int nq4 = D * D / 4, nk4 = KVD * D / 4, nv4 = KVD * D / 4, np4 = D * D / 4;
    int tot = nr + nx4 + nq4 + nk4 + nv4 + np4;
    k_prep<<<(tot + 255) / 256, 256, 0, stream>>>(x, Wq, Wk, Wv, Wp, x_bf, wqkv, wp_bf, cosT,
                                                  sinT, l2b, nr, nx4, nq4, nk4, nv4, np4);
  }

  dim3 gqkv(NQKV / 384, M / 128);  // 8 x 32 = 256 blocks = 1/CU
  k_gemm_qkv8<<<gqkv, 512, 0, stream>>>(x_bf, wqkv, q_bf, k_bf, v_t, M, D);

  float qscale = 1.4426950408889634f / sqrtf(128.0f);
  {
    int MH_ = M * H, MKH_ = M * KH;
    int rows = MH_ + MKH_;
    k_rmsnorm_rope2<<<rows / 4, 256, 0, stream>>>(q_bf, k_bf, cosT, sinT, gain, MH_, MKH_, S,
                                                  qscale);
  }

  dim3 blk(256);
  dim3 ga(B * H, S / 128);  // 512 blocks, paired q-tiles {y, 31-y}
  k_flash_attn<<<ga, blk, 0, stream>>>(q_bf, k_bf, v_t, ao_bf, S, H, KH, M);

  dim3 gp(D / 256, M / 128);  // 8 x 32 = 256 blocks = 1/CU
  k_gemm_bt8<<<gp, 512, 0, stream>>>(ao_bf, wp_bf, out, M, D, D);
}